// Round 3
// baseline (778.659 us; speedup 1.0000x reference)
//
#include <hip/hip_runtime.h>
#include <cstdint>
#include <cstddef>

#define H 8
#define C 16
#define DHID 128
#define LDSP (DHID + 1)   // padded LDS row: kills 8/16-way bank conflicts in score loops
#define RPB 16            // rows per block in GEMV-style kernels
#define NEG_SLOPE 0.2f
#define GN_EPS 1e-5f

#define SCAN_T 256
#define SCAN_I 4       // 1024 elements per scan block

__device__ __forceinline__ void atomAddF(float* p, float v) {
    __hip_atomic_fetch_add(p, v, __ATOMIC_RELAXED, __HIP_MEMORY_SCOPE_AGENT);
}

__device__ __forceinline__ unsigned short f2bf(float f) {
    uint32_t u = __float_as_uint(f);
    uint32_t r = (u + 0x7FFFu + ((u >> 16) & 1u)) >> 16;
    return (unsigned short)r;
}
__device__ __forceinline__ float bf2f(unsigned short b) {
    return __uint_as_float(((uint32_t)b) << 16);
}

// ---------------------------------------------------------------------------
// Fold attention vectors into weight matrices: V[k][h] = sum_c W[k][h*16+c]*att[h][c]
// ---------------------------------------------------------------------------
__global__ void fold_kernel(const float* __restrict__ Wsw, const float* __restrict__ asw,
                            const float* __restrict__ Wdw, const float* __restrict__ adw,
                            const float* __restrict__ Wsc, const float* __restrict__ asc,
                            const float* __restrict__ Wdc, const float* __restrict__ adc,
                            const float* __restrict__ bias_w, const float* __restrict__ bias_c,
                            float* __restrict__ Vsw, float* __restrict__ Vdw,
                            float* __restrict__ Vsc, float* __restrict__ Vdc,
                            float* __restrict__ bsum) {
    int k = threadIdx.x;      // 0..127
    int which = blockIdx.x;   // 0..3
    const float* W = which == 0 ? Wsw : which == 1 ? Wdw : which == 2 ? Wsc : Wdc;
    const float* A = which == 0 ? asw : which == 1 ? adw : which == 2 ? asc : adc;
    float* V = which == 0 ? Vsw : which == 1 ? Vdw : which == 2 ? Vsc : Vdc;
    for (int h = 0; h < H; ++h) {
        float s = 0.f;
        for (int c = 0; c < C; ++c) s += W[k * DHID + h * C + c] * A[h * C + c];
        V[k * H + h] = s;
    }
    if (which == 0) bsum[k] = bias_w[k] + bias_c[k];
}

// ---------------------------------------------------------------------------
// Paper projection: emb = relu(x@Wlin+b) in LDS; xs_c = emb@Wsrc_c (bf16 out);
// three 8-wide score projections. One 128-thread block handles RPB rows.
// ---------------------------------------------------------------------------
__global__ void paper_proj(const float* __restrict__ x,
                           const float* __restrict__ Wlin, const float* __restrict__ blin,
                           const float* __restrict__ Wsrc_c,
                           const float* __restrict__ Vd_w, const float* __restrict__ Vs_c,
                           const float* __restrict__ Vd_c,
                           unsigned short* __restrict__ xs_c,
                           float* __restrict__ a_d_w, float* __restrict__ a_s_c,
                           float* __restrict__ a_d_c, int Np) {
    __shared__ float xr[RPB][LDSP];
    __shared__ float er[RPB][LDSP];
    int t = threadIdx.x;
    long row0 = (long)blockIdx.x * RPB;
    int nr = (int)min((long)RPB, (long)Np - row0);
    for (int r = 0; r < nr; ++r) xr[r][t] = x[(row0 + r) * DHID + t];
    __syncthreads();
    float acc[RPB];
    float bl = blin[t];
#pragma unroll
    for (int r = 0; r < RPB; ++r) acc[r] = bl;
    for (int k = 0; k < DHID; ++k) {
        float w = Wlin[k * DHID + t];
#pragma unroll
        for (int r = 0; r < RPB; ++r) acc[r] += xr[r][k] * w;
    }
    for (int r = 0; r < nr; ++r) er[r][t] = fmaxf(acc[r], 0.f);
    __syncthreads();
#pragma unroll
    for (int r = 0; r < RPB; ++r) acc[r] = 0.f;
    for (int k = 0; k < DHID; ++k) {
        float w = Wsrc_c[k * DHID + t];
#pragma unroll
        for (int r = 0; r < RPB; ++r) acc[r] += er[r][k] * w;
    }
    for (int r = 0; r < nr; ++r) xs_c[(row0 + r) * DHID + t] = f2bf(acc[r]);
    // attention scores: thread t -> (row r = t>>3, head h = t&7); 16*8 = 128 threads
    {
        int r = t >> 3, h = t & 7;
        if (r < nr) {
            float sdw = 0.f, ssc = 0.f, sdc = 0.f;
            for (int k = 0; k < DHID; ++k) {
                float e = er[r][k];
                sdw += e * Vd_w[k * H + h];
                ssc += e * Vs_c[k * H + h];
                sdc += e * Vd_c[k * H + h];
            }
            a_d_w[(row0 + r) * H + h] = sdw;
            a_s_c[(row0 + r) * H + h] = ssc;
            a_d_c[(row0 + r) * H + h] = sdc;
        }
    }
}

// ---------------------------------------------------------------------------
// Author projection: emb = relu(x@Wlin+b), xs_w = emb@Wsrc_w (bf16), a_s_w scores.
// ---------------------------------------------------------------------------
__global__ void author_proj(const float* __restrict__ x,
                            const float* __restrict__ Wlin, const float* __restrict__ blin,
                            const float* __restrict__ Wsrc_w, const float* __restrict__ Vs_w,
                            unsigned short* __restrict__ xs_w, float* __restrict__ a_s_w, int Na) {
    __shared__ float xr[RPB][LDSP];
    __shared__ float er[RPB][LDSP];
    int t = threadIdx.x;
    long row0 = (long)blockIdx.x * RPB;
    int nr = (int)min((long)RPB, (long)Na - row0);
    for (int r = 0; r < nr; ++r) xr[r][t] = x[(row0 + r) * DHID + t];
    __syncthreads();
    float acc[RPB];
    float bl = blin[t];
#pragma unroll
    for (int r = 0; r < RPB; ++r) acc[r] = bl;
    for (int k = 0; k < DHID; ++k) {
        float w = Wlin[k * DHID + t];
#pragma unroll
        for (int r = 0; r < RPB; ++r) acc[r] += xr[r][k] * w;
    }
    for (int r = 0; r < nr; ++r) er[r][t] = fmaxf(acc[r], 0.f);
    __syncthreads();
#pragma unroll
    for (int r = 0; r < RPB; ++r) acc[r] = 0.f;
    for (int k = 0; k < DHID; ++k) {
        float w = Wsrc_w[k * DHID + t];
#pragma unroll
        for (int r = 0; r < RPB; ++r) acc[r] += er[r][k] * w;
    }
    for (int r = 0; r < nr; ++r) xs_w[(row0 + r) * DHID + t] = f2bf(acc[r]);
    {
        int r = t >> 3, h = t & 7;
        if (r < nr) {
            float s = 0.f;
            for (int k = 0; k < DHID; ++k) s += er[r][k] * Vs_w[k * H + h];
            a_s_w[(row0 + r) * H + h] = s;
        }
    }
}

// ---------------------------------------------------------------------------
// CSR build: degree histogram (edges + implicit self-loops)
// ---------------------------------------------------------------------------
__global__ void deg_hist(const int* __restrict__ dst, int E, int nself, int* __restrict__ deg) {
    int i = blockIdx.x * blockDim.x + threadIdx.x;
    if (i < E) atomicAdd(&deg[dst[i]], 1);
    else if (i < E + nself) atomicAdd(&deg[i - E], 1);
}

// Exclusive scan, pass 1: per-block scan + block totals. Safe in-place (out==in).
__global__ void scan1(const int* __restrict__ in, int n, int* __restrict__ out,
                      int* __restrict__ bsums) {
    __shared__ int sh[SCAN_T];
    int t = threadIdx.x;
    long base = (long)blockIdx.x * SCAN_T * SCAN_I;
    int v[SCAN_I];
    int s = 0;
#pragma unroll
    for (int j = 0; j < SCAN_I; ++j) {
        long idx = base + (long)t * SCAN_I + j;
        v[j] = (idx < n) ? in[idx] : 0;
        s += v[j];
    }
    sh[t] = s;
    __syncthreads();
    for (int off = 1; off < SCAN_T; off <<= 1) {
        int x = (t >= off) ? sh[t - off] : 0;
        __syncthreads();
        sh[t] += x;
        __syncthreads();
    }
    int run = sh[t] - s;   // exclusive prefix of this thread's chunk
#pragma unroll
    for (int j = 0; j < SCAN_I; ++j) {
        long idx = base + (long)t * SCAN_I + j;
        if (idx < n) out[idx] = run;
        run += v[j];
    }
    if (t == SCAN_T - 1) bsums[blockIdx.x] = sh[SCAN_T - 1];
}

// pass 3: add block offsets, write sentinel, init cursors
__global__ void scan3(int* __restrict__ off, const int* __restrict__ bsums, int n, int total,
                      int* __restrict__ cur) {
    int i = blockIdx.x * blockDim.x + threadIdx.x;
    if (i < n) {
        int v = off[i] + bsums[i / (SCAN_T * SCAN_I)];
        off[i] = v;
        cur[i] = v;
    }
    if (i == n) off[n] = total;
}

// scatter: fill per-dst src lists using atomic cursors
__global__ void csr_scatter(const int* __restrict__ src, const int* __restrict__ dst,
                            int E, int nself, int* __restrict__ cur, int* __restrict__ srcarr) {
    int i = blockIdx.x * blockDim.x + threadIdx.x;
    if (i >= E + nself) return;
    int s, d;
    if (i < E) { s = src[i]; d = dst[i]; } else { s = d = i - E; }
    int pos = atomicAdd(&cur[d], 1);
    srcarr[pos] = s;
}

// ---------------------------------------------------------------------------
// Gather: one 128-thread block per paper, SINGLE PASS per edge type:
//   num = sum_i p_i * xs[src_i],  den = sum_i p_i,  out += num/(den+1e-16)
// thread t owns output element t; head h = t>>4. xs is bf16.
// ---------------------------------------------------------------------------
__global__ void gat_gather(const int* __restrict__ offw, const int* __restrict__ srcw,
                           const int* __restrict__ offc, const int* __restrict__ srcc,
                           const float* __restrict__ a_s_w, const float* __restrict__ a_d_w,
                           const float* __restrict__ a_s_c, const float* __restrict__ a_d_c,
                           const unsigned short* __restrict__ xs_w,
                           const unsigned short* __restrict__ xs_c,
                           float* __restrict__ gat, int Np) {
    int d = blockIdx.x;
    int t = threadIdx.x;
    int h = t >> 4;
    float out = 0.f;
    // writes edges (author -> paper)
    {
        int b0 = offw[d], b1 = offw[d + 1];
        float ad = a_d_w[(long)d * H + h];
        float num = 0.f, den = 0.f;
        for (int i = b0; i < b1; ++i) {
            int s = srcw[i];
            float e = a_s_w[(long)s * H + h] + ad;
            e = e > 0.f ? e : NEG_SLOPE * e;
            float p = __expf(e);
            den += p;
            num += p * bf2f(xs_w[(long)s * DHID + t]);
        }
        out += num / (den + 1e-16f);
    }
    // cites edges (paper -> paper)
    {
        int b0 = offc[d], b1 = offc[d + 1];
        float ad = a_d_c[(long)d * H + h];
        float num = 0.f, den = 0.f;
        for (int i = b0; i < b1; ++i) {
            int s = srcc[i];
            float e = a_s_c[(long)s * H + h] + ad;
            e = e > 0.f ? e : NEG_SLOPE * e;
            float p = __expf(e);
            den += p;
            num += p * bf2f(xs_c[(long)s * DHID + t]);
        }
        out += num / (den + 1e-16f);
    }
    gat[(long)d * DHID + t] = out;
}

// ---------------------------------------------------------------------------
// GraphNorm reduction: per-column sum and sum-of-squares of (gat + bsum)
// ---------------------------------------------------------------------------
#define GN_ROWS 128
__global__ void gn_reduce(const float* __restrict__ gat, const float* __restrict__ bsum,
                          float* __restrict__ colsum, float* __restrict__ colsumsq, int Np) {
    int t = threadIdx.x;
    long r0 = (long)blockIdx.x * GN_ROWS;
    long r1 = min(r0 + GN_ROWS, (long)Np);
    float b = bsum[t], s1 = 0.f, s2 = 0.f;
    for (long r = r0; r < r1; ++r) {
        float xv = gat[r * DHID + t] + b;
        s1 += xv;
        s2 += xv * xv;
    }
    atomAddF(colsum + t, s1);
    atomAddF(colsumsq + t, s2);
}

// ---------------------------------------------------------------------------
// Final paper: graphnorm + @W2 + b2 -> d_out
// var = E[x^2] - mu^2 * ms * (2 - ms)   (exact expansion of mean((x-ms*mu)^2))
// ---------------------------------------------------------------------------
__global__ void final_paper(const float* __restrict__ gat, const float* __restrict__ bsum,
                            const float* __restrict__ colsum, const float* __restrict__ colsumsq,
                            const float* __restrict__ gnw, const float* __restrict__ gnb,
                            const float* __restrict__ gnm,
                            const float* __restrict__ W2, const float* __restrict__ b2,
                            float* __restrict__ out, int Np) {
    __shared__ float nrm[RPB][LDSP];
    int t = threadIdx.x;
    long row0 = (long)blockIdx.x * RPB;
    float invN = 1.f / (float)Np;
    float mu = colsum[t] * invN;
    float ms = gnm[t];
    float ex2 = colsumsq[t] * invN;
    float var = ex2 - mu * mu * ms * (2.f - ms);
    float scale = gnw[t] * rsqrtf(var + GN_EPS);
    float b = bsum[t], gb = gnb[t];
    int nr = (int)min((long)RPB, (long)Np - row0);
    for (int r = 0; r < nr; ++r) {
        float xv = gat[(row0 + r) * DHID + t] + b;
        nrm[r][t] = (xv - ms * mu) * scale + gb;
    }
    __syncthreads();
    float acc[RPB];
    float bb = b2[t];
#pragma unroll
    for (int r = 0; r < RPB; ++r) acc[r] = bb;
    for (int k = 0; k < DHID; ++k) {
        float w = W2[k * DHID + t];
#pragma unroll
        for (int r = 0; r < RPB; ++r) acc[r] += nrm[r][k] * w;
    }
    for (int r = 0; r < nr; ++r) out[(row0 + r) * DHID + t] = acc[r];
}

// ---------------------------------------------------------------------------
// Author output: gnorm(zeros) == gnb, so every row = gnb@W2_author + b2_author
// ---------------------------------------------------------------------------
__global__ void author_row(const float* __restrict__ gnb_a, const float* __restrict__ W2a,
                           const float* __restrict__ b2a, float* __restrict__ row_a) {
    int t = threadIdx.x;
    float acc = b2a[t];
    for (int k = 0; k < DHID; ++k) acc += gnb_a[k] * W2a[k * DHID + t];
    row_a[t] = acc;
}

__global__ void fill_author(const float* __restrict__ row_a, float* __restrict__ out, long n) {
    long i = (long)blockIdx.x * blockDim.x + threadIdx.x;
    if (i < n) out[i] = row_a[i & (DHID - 1)];
}

// ---------------------------------------------------------------------------
extern "C" void kernel_launch(void* const* d_in, const int* in_sizes, int n_in,
                              void* d_out, int out_size, void* d_ws, size_t ws_size,
                              hipStream_t stream) {
    const float* x_p   = (const float*)d_in[0];
    const float* x_a   = (const float*)d_in[1];
    const int*   e_w   = (const int*)d_in[2];
    const int*   e_c   = (const int*)d_in[3];
    const float* Wlp   = (const float*)d_in[4];
    const float* blp   = (const float*)d_in[5];
    const float* Wla   = (const float*)d_in[6];
    const float* bla   = (const float*)d_in[7];
    const float* Wsw   = (const float*)d_in[8];
    const float* Wdw   = (const float*)d_in[9];
    const float* asw   = (const float*)d_in[10];
    const float* adw   = (const float*)d_in[11];
    const float* bw    = (const float*)d_in[12];
    const float* Wsc   = (const float*)d_in[13];
    const float* Wdc   = (const float*)d_in[14];
    const float* asc   = (const float*)d_in[15];
    const float* adc   = (const float*)d_in[16];
    const float* bc    = (const float*)d_in[17];
    const float* gnw_p = (const float*)d_in[18];
    const float* gnb_p = (const float*)d_in[19];
    const float* gnm_p = (const float*)d_in[20];
    const float* gnb_a = (const float*)d_in[22];
    const float* W2p   = (const float*)d_in[24];
    const float* b2p   = (const float*)d_in[25];
    const float* W2a   = (const float*)d_in[26];
    const float* b2a   = (const float*)d_in[27];

    int Np = in_sizes[0] / DHID;
    int Na = in_sizes[1] / DHID;
    int Ew = in_sizes[2] / 2;
    int Ec = in_sizes[3] / 2;
    int nself_w = Na < Np ? Na : Np;
    int nself_c = Np;
    int tot_w = Ew + nself_w;
    int tot_c = Ec + nself_c;

    float* ws = (float*)d_ws;
    float* gat   = ws;                                 // Np*128
    float* a_s_w = gat + (size_t)Np * DHID;            // Na*8
    float* a_d_w = a_s_w + (size_t)Na * H;             // Np*8
    float* a_s_c = a_d_w + (size_t)Np * H;             // Np*8
    float* a_d_c = a_s_c + (size_t)Np * H;             // Np*8
    float* Vs_w  = a_d_c + (size_t)Np * H;             // 128*8 each
    float* Vd_w  = Vs_w + DHID * H;
    float* Vs_c  = Vd_w + DHID * H;
    float* Vd_c  = Vs_c + DHID * H;
    float* bsum  = Vd_c + DHID * H;                    // 128
    float* row_a = bsum + DHID;                        // 128
    // ---- zeroed region (one contiguous memset) ----
    float* colsum   = row_a + DHID;                    // 128
    float* colsumsq = colsum + DHID;                   // 128
    int*   degw     = (int*)(colsumsq + DHID);         // Np
    int*   degc     = degw + Np;                       // Np
    size_t zero_bytes = (2 * DHID) * sizeof(float) + 2 * (size_t)Np * sizeof(int);
    // ---- CSR arrays ----
    int* offw  = degc + Np;                            // Np+1
    int* offc  = offw + Np + 1;                        // Np+1
    int* curw  = offc + Np + 1;                        // Np
    int* curc  = curw + Np;                            // Np
    int* srcw  = curc + Np;                            // tot_w
    int* srcc  = srcw + tot_w;                         // tot_c
    int* bs1   = srcc + tot_c;                         // 512
    int* bs2   = bs1 + 512;                            // 512
    // ---- bf16 message arrays ----
    unsigned short* xs_w = (unsigned short*)(bs2 + 512);   // Na*128 bf16
    unsigned short* xs_c = xs_w + (size_t)Na * DHID;       // Np*128 bf16

    hipMemsetAsync(colsum, 0, zero_bytes, stream);

    fold_kernel<<<4, 128, 0, stream>>>(Wsw, asw, Wdw, adw, Wsc, asc, Wdc, adc,
                                       bw, bc, Vs_w, Vd_w, Vs_c, Vd_c, bsum);

    paper_proj<<<(Np + RPB - 1) / RPB, 128, 0, stream>>>(
        x_p, Wlp, blp, Wsc, Vd_w, Vs_c, Vd_c, xs_c, a_d_w, a_s_c, a_d_c, Np);
    author_proj<<<(Na + RPB - 1) / RPB, 128, 0, stream>>>(
        x_a, Wla, bla, Wsw, Vs_w, xs_w, a_s_w, Na);

    // ---- CSR build ----
    deg_hist<<<(tot_w + 255) / 256, 256, 0, stream>>>(e_w + Ew, Ew, nself_w, degw);
    deg_hist<<<(tot_c + 255) / 256, 256, 0, stream>>>(e_c + Ec, Ec, nself_c, degc);
    int nb = (Np + SCAN_T * SCAN_I - 1) / (SCAN_T * SCAN_I);
    scan1<<<nb, SCAN_T, 0, stream>>>(degw, Np, offw, bs1);
    scan1<<<nb, SCAN_T, 0, stream>>>(degc, Np, offc, bs2);
    scan1<<<1, SCAN_T, 0, stream>>>(bs1, nb, bs1, bs1 + 480);   // in-place, dummy total slot
    scan1<<<1, SCAN_T, 0, stream>>>(bs2, nb, bs2, bs2 + 480);
    scan3<<<(Np + 256) / 256, 256, 0, stream>>>(offw, bs1, Np, tot_w, curw);
    scan3<<<(Np + 256) / 256, 256, 0, stream>>>(offc, bs2, Np, tot_c, curc);
    csr_scatter<<<(tot_w + 255) / 256, 256, 0, stream>>>(e_w, e_w + Ew, Ew, nself_w, curw, srcw);
    csr_scatter<<<(tot_c + 255) / 256, 256, 0, stream>>>(e_c, e_c + Ec, Ec, nself_c, curc, srcc);

    // ---- fused single-pass gather (both edge types, no atomics) ----
    gat_gather<<<Np, 128, 0, stream>>>(offw, srcw, offc, srcc,
                                       a_s_w, a_d_w, a_s_c, a_d_c,
                                       xs_w, xs_c, gat, Np);

    gn_reduce<<<(Np + GN_ROWS - 1) / GN_ROWS, 128, 0, stream>>>(gat, bsum, colsum, colsumsq, Np);

    final_paper<<<(Np + RPB - 1) / RPB, 128, 0, stream>>>(
        gat, bsum, colsum, colsumsq, gnw_p, gnb_p, gnm_p, W2p, b2p, (float*)d_out, Np);

    author_row<<<1, 128, 0, stream>>>(gnb_a, W2a, b2a, row_a);
    {
        long n = (long)Na * DHID;
        fill_author<<<(n + 255) / 256, 256, 0, stream>>>(row_a, (float*)d_out + (size_t)Np * DHID, n);
    }
}

// Round 4
// 447.444 us; speedup vs baseline: 1.7402x; 1.7402x over previous
//
#include <hip/hip_runtime.h>
#include <cstdint>
#include <cstddef>

#define H 8
#define C 16
#define DHID 128
#define BM 64            // rows per MFMA block
#define LDST 136         // padded LDS row stride (bf16 elems): 272B, 16B-aligned, de-conflicts b128 reads
#define NEG_SLOPE 0.2f
#define GN_EPS 1e-5f

#define SCAN_T 256
#define SCAN_I 4       // 1024 elements per scan block

typedef __attribute__((ext_vector_type(8))) short short8;
typedef __attribute__((ext_vector_type(4))) float f32x4;

__device__ __forceinline__ void atomAddF(float* p, float v) {
    __hip_atomic_fetch_add(p, v, __ATOMIC_RELAXED, __HIP_MEMORY_SCOPE_AGENT);
}

__device__ __forceinline__ unsigned short f2bf(float f) {
    uint32_t u = __float_as_uint(f);
    uint32_t r = (u + 0x7FFFu + ((u >> 16) & 1u)) >> 16;
    return (unsigned short)r;
}
__device__ __forceinline__ float bf2f(unsigned short b) {
    return __uint_as_float(((uint32_t)b) << 16);
}

// ---------------------------------------------------------------------------
// Fold attention vectors into combined score matrices:
//   Vp[k][0..7]=Wdst_w@attd_w, [8..15]=Wsrc_c@atts_c, [16..23]=Wdst_c@attd_c
//   Va[k][0..7]=Wsrc_w@atts_w ;  bsum = bias_w + bias_c
// ---------------------------------------------------------------------------
__global__ void fold_kernel(const float* __restrict__ Wsw, const float* __restrict__ asw,
                            const float* __restrict__ Wdw, const float* __restrict__ adw,
                            const float* __restrict__ Wsc, const float* __restrict__ asc,
                            const float* __restrict__ Wdc, const float* __restrict__ adc,
                            const float* __restrict__ bias_w, const float* __restrict__ bias_c,
                            float* __restrict__ Vp, float* __restrict__ Va,
                            float* __restrict__ bsum) {
    int k = threadIdx.x;      // 0..127
    int which = blockIdx.x;   // 0..3
    const float* W = which == 0 ? Wsw : which == 1 ? Wdw : which == 2 ? Wsc : Wdc;
    const float* A = which == 0 ? asw : which == 1 ? adw : which == 2 ? asc : adc;
    for (int h = 0; h < H; ++h) {
        float s = 0.f;
        for (int c = 0; c < C; ++c) s += W[k * DHID + h * C + c] * A[h * C + c];
        if (which == 0) Va[k * H + h] = s;
        else Vp[k * 24 + (which - 1) * H + h] = s;
    }
    if (which == 0) bsum[k] = bias_w[k] + bias_c[k];
}

// ---------------------------------------------------------------------------
// Pack an f32 matrix W[128][ldw] (use cols < ncols, rest zero) into bf16 MFMA
// B-fragments: out[((nt*4+kk)*64+lane)*8+i] = W[kk*32+(lane>>4)*8+i][nt*16+(lane&15)]
// (B layout for mfma_f32_16x16x32_bf16: col=lane&15, k=8*(lane>>4)+i, K-step kk*32)
// ---------------------------------------------------------------------------
__global__ void pack_b(const float* __restrict__ W, int ldw, int ncols,
                       unsigned short* __restrict__ out, int ntiles) {
    int idx = blockIdx.x * 256 + threadIdx.x;     // one per (nt,kk,lane)
    if (idx >= ntiles * 4 * 64) return;
    int lane = idx & 63, kk = (idx >> 6) & 3, nt = idx >> 8;
    int col = nt * 16 + (lane & 15);
    int k0 = kk * 32 + ((lane >> 4) << 3);
    for (int i = 0; i < 8; ++i)
        out[idx * 8 + i] = (col < ncols) ? f2bf(W[(k0 + i) * ldw + col]) : (unsigned short)0;
}

// ---------------------------------------------------------------------------
// MFMA projection: 256 thr / 4 waves / 64 rows.
//   emb = relu(x@Wlin+b)  (LDS roundtrip, bf16)
//   xs  = emb@Wsrc -> global bf16
//   scores = emb@Vsc -> a0/a1/a2 ([N][8] each); NSC score tiles (2=paper,1=author)
// ---------------------------------------------------------------------------
template <int NSC>
__global__ __launch_bounds__(256) void proj_mfma(
    const float* __restrict__ x, int nrows,
    const unsigned short* __restrict__ WlinP, const float* __restrict__ blin,
    const unsigned short* __restrict__ WsrcP, const unsigned short* __restrict__ VscP,
    unsigned short* __restrict__ xs,
    float* __restrict__ a0, float* __restrict__ a1, float* __restrict__ a2) {
    __shared__ unsigned short xt[BM * LDST];
    int t = threadIdx.x;
    int lane = t & 63, w = t >> 6;
    long row0 = (long)blockIdx.x * BM;
    // ---- stage x tile as bf16 pairs (coalesced, conflict-free b32 writes) ----
    for (int it = 0; it < 16; ++it) {
        int idx2 = t + it * 256;              // 4096 col-pairs = 64 rows x 64 pairs
        int r = idx2 >> 6, cp = idx2 & 63;
        long gr = row0 + r;
        float v0 = 0.f, v1 = 0.f;
        if (gr < nrows) { v0 = x[gr * DHID + 2 * cp]; v1 = x[gr * DHID + 2 * cp + 1]; }
        uint32_t pk = (uint32_t)f2bf(v0) | ((uint32_t)f2bf(v1) << 16);
        *reinterpret_cast<uint32_t*>(&xt[r * LDST + 2 * cp]) = pk;
    }
    __syncthreads();
    int arow = w * 16 + (lane & 15);          // A-fragment row for this lane
    int koff = (lane >> 4) << 3;              // k sub-offset
    short8 af[4];
#pragma unroll
    for (int kk = 0; kk < 4; ++kk)
        af[kk] = *reinterpret_cast<const short8*>(&xt[arow * LDST + kk * 32 + koff]);
    // ---- GEMM1: emb = x @ Wlin ----
    const short8* Bl = reinterpret_cast<const short8*>(WlinP);
    f32x4 acc[8];
#pragma unroll
    for (int nt = 0; nt < 8; ++nt) {
        f32x4 a = {0.f, 0.f, 0.f, 0.f};
#pragma unroll
        for (int kk = 0; kk < 4; ++kk)
            a = __builtin_amdgcn_mfma_f32_16x16x32_bf16(af[kk], Bl[(nt * 4 + kk) * 64 + lane], a, 0, 0, 0);
        acc[nt] = a;
    }
    __syncthreads();
    // ---- bias + relu, write emb (bf16) back into same LDS tile ----
    int orow = w * 16 + ((lane >> 4) << 2);   // C-layout: row = 4*(lane>>4)+reg
    int ccol = lane & 15;
#pragma unroll
    for (int nt = 0; nt < 8; ++nt) {
        float b = blin[nt * 16 + ccol];
#pragma unroll
        for (int r = 0; r < 4; ++r) {
            float e = fmaxf(acc[nt][r] + b, 0.f);
            xt[(orow + r) * LDST + nt * 16 + ccol] = f2bf(e);
        }
    }
    __syncthreads();
#pragma unroll
    for (int kk = 0; kk < 4; ++kk)
        af[kk] = *reinterpret_cast<const short8*>(&xt[arow * LDST + kk * 32 + koff]);
    // ---- GEMM2: xs = emb @ Wsrc ----
    const short8* Bs = reinterpret_cast<const short8*>(WsrcP);
#pragma unroll
    for (int nt = 0; nt < 8; ++nt) {
        f32x4 a = {0.f, 0.f, 0.f, 0.f};
#pragma unroll
        for (int kk = 0; kk < 4; ++kk)
            a = __builtin_amdgcn_mfma_f32_16x16x32_bf16(af[kk], Bs[(nt * 4 + kk) * 64 + lane], a, 0, 0, 0);
        acc[nt] = a;
    }
    // ---- scores: emb @ Vsc ----
    const short8* Bv = reinterpret_cast<const short8*>(VscP);
    f32x4 sacc0 = {0.f, 0.f, 0.f, 0.f}, sacc1 = {0.f, 0.f, 0.f, 0.f};
#pragma unroll
    for (int kk = 0; kk < 4; ++kk)
        sacc0 = __builtin_amdgcn_mfma_f32_16x16x32_bf16(af[kk], Bv[kk * 64 + lane], sacc0, 0, 0, 0);
    if (NSC > 1) {
#pragma unroll
        for (int kk = 0; kk < 4; ++kk)
            sacc1 = __builtin_amdgcn_mfma_f32_16x16x32_bf16(af[kk], Bv[(4 + kk) * 64 + lane], sacc1, 0, 0, 0);
    }
    // ---- epilogue: xs (bf16) ----
#pragma unroll
    for (int nt = 0; nt < 8; ++nt) {
#pragma unroll
        for (int r = 0; r < 4; ++r) {
            long gr = row0 + orow + r;
            if (gr < nrows) xs[gr * DHID + nt * 16 + ccol] = f2bf(acc[nt][r]);
        }
    }
    // ---- epilogue: scores.  packed col -> (which, head): 0-7 a0, 8-15 a1, 16-23 a2 ----
#pragma unroll
    for (int st = 0; st < NSC; ++st) {
        int scol = st * 16 + ccol;
        int h = scol & 7, which = scol >> 3;
        float* ap = which == 0 ? a0 : which == 1 ? a1 : which == 2 ? a2 : nullptr;
        if (ap) {
            f32x4 s = st == 0 ? sacc0 : sacc1;
#pragma unroll
            for (int r = 0; r < 4; ++r) {
                long gr = row0 + orow + r;
                if (gr < nrows) ap[gr * H + h] = s[r];
            }
        }
    }
}

// ---------------------------------------------------------------------------
// CSR build: degree histogram (edges + implicit self-loops)
// ---------------------------------------------------------------------------
__global__ void deg_hist(const int* __restrict__ dst, int E, int nself, int* __restrict__ deg) {
    int i = blockIdx.x * blockDim.x + threadIdx.x;
    if (i < E) atomicAdd(&deg[dst[i]], 1);
    else if (i < E + nself) atomicAdd(&deg[i - E], 1);
}

// Exclusive scan, pass 1: per-block scan + block totals. Safe in-place (out==in).
__global__ void scan1(const int* __restrict__ in, int n, int* __restrict__ out,
                      int* __restrict__ bsums) {
    __shared__ int sh[SCAN_T];
    int t = threadIdx.x;
    long base = (long)blockIdx.x * SCAN_T * SCAN_I;
    int v[SCAN_I];
    int s = 0;
#pragma unroll
    for (int j = 0; j < SCAN_I; ++j) {
        long idx = base + (long)t * SCAN_I + j;
        v[j] = (idx < n) ? in[idx] : 0;
        s += v[j];
    }
    sh[t] = s;
    __syncthreads();
    for (int off = 1; off < SCAN_T; off <<= 1) {
        int x = (t >= off) ? sh[t - off] : 0;
        __syncthreads();
        sh[t] += x;
        __syncthreads();
    }
    int run = sh[t] - s;
#pragma unroll
    for (int j = 0; j < SCAN_I; ++j) {
        long idx = base + (long)t * SCAN_I + j;
        if (idx < n) out[idx] = run;
        run += v[j];
    }
    if (t == SCAN_T - 1) bsums[blockIdx.x] = sh[SCAN_T - 1];
}

// pass 3: add block offsets, write sentinel, init cursors
__global__ void scan3(int* __restrict__ off, const int* __restrict__ bsums, int n, int total,
                      int* __restrict__ cur) {
    int i = blockIdx.x * blockDim.x + threadIdx.x;
    if (i < n) {
        int v = off[i] + bsums[i / (SCAN_T * SCAN_I)];
        off[i] = v;
        cur[i] = v;
    }
    if (i == n) off[n] = total;
}

// scatter: fill per-dst src lists using atomic cursors
__global__ void csr_scatter(const int* __restrict__ src, const int* __restrict__ dst,
                            int E, int nself, int* __restrict__ cur, int* __restrict__ srcarr) {
    int i = blockIdx.x * blockDim.x + threadIdx.x;
    if (i >= E + nself) return;
    int s, d;
    if (i < E) { s = src[i]; d = dst[i]; } else { s = d = i - E; }
    int pos = atomicAdd(&cur[d], 1);
    srcarr[pos] = s;
}

// ---------------------------------------------------------------------------
// Gather: one 128-thread block per paper, SINGLE PASS per edge type:
//   num = sum_i p_i * xs[src_i],  den = sum_i p_i,  out += num/(den+1e-16)
// ---------------------------------------------------------------------------
__global__ void gat_gather(const int* __restrict__ offw, const int* __restrict__ srcw,
                           const int* __restrict__ offc, const int* __restrict__ srcc,
                           const float* __restrict__ a_s_w, const float* __restrict__ a_d_w,
                           const float* __restrict__ a_s_c, const float* __restrict__ a_d_c,
                           const unsigned short* __restrict__ xs_w,
                           const unsigned short* __restrict__ xs_c,
                           float* __restrict__ gat, int Np) {
    int d = blockIdx.x;
    int t = threadIdx.x;
    int h = t >> 4;
    float out = 0.f;
    {
        int b0 = offw[d], b1 = offw[d + 1];
        float ad = a_d_w[(long)d * H + h];
        float num = 0.f, den = 0.f;
        for (int i = b0; i < b1; ++i) {
            int s = srcw[i];
            float e = a_s_w[(long)s * H + h] + ad;
            e = e > 0.f ? e : NEG_SLOPE * e;
            float p = __expf(e);
            den += p;
            num += p * bf2f(xs_w[(long)s * DHID + t]);
        }
        out += num / (den + 1e-16f);
    }
    {
        int b0 = offc[d], b1 = offc[d + 1];
        float ad = a_d_c[(long)d * H + h];
        float num = 0.f, den = 0.f;
        for (int i = b0; i < b1; ++i) {
            int s = srcc[i];
            float e = a_s_c[(long)s * H + h] + ad;
            e = e > 0.f ? e : NEG_SLOPE * e;
            float p = __expf(e);
            den += p;
            num += p * bf2f(xs_c[(long)s * DHID + t]);
        }
        out += num / (den + 1e-16f);
    }
    gat[(long)d * DHID + t] = out;
}

// ---------------------------------------------------------------------------
// GraphNorm reduction: per-column sum and sum-of-squares of (gat + bsum)
// ---------------------------------------------------------------------------
#define GN_ROWS 128
__global__ void gn_reduce(const float* __restrict__ gat, const float* __restrict__ bsum,
                          float* __restrict__ colsum, float* __restrict__ colsumsq, int Np) {
    int t = threadIdx.x;
    long r0 = (long)blockIdx.x * GN_ROWS;
    long r1 = min(r0 + GN_ROWS, (long)Np);
    float b = bsum[t], s1 = 0.f, s2 = 0.f;
    for (long r = r0; r < r1; ++r) {
        float xv = gat[r * DHID + t] + b;
        s1 += xv;
        s2 += xv * xv;
    }
    atomAddF(colsum + t, s1);
    atomAddF(colsumsq + t, s2);
}

// ---------------------------------------------------------------------------
// Final paper via MFMA: nrm = (gat+bsum)*cscale + cshift (bf16 in LDS), @W2 + b2.
// var = E[x^2] - mu^2*ms*(2-ms) exactly; nrm folded to per-col scale/shift.
// ---------------------------------------------------------------------------
__global__ __launch_bounds__(256) void final_mfma(
    const float* __restrict__ gat, const float* __restrict__ bsum,
    const float* __restrict__ colsum, const float* __restrict__ colsumsq,
    const float* __restrict__ gnw, const float* __restrict__ gnb,
    const float* __restrict__ gnm,
    const unsigned short* __restrict__ W2P, const float* __restrict__ b2,
    float* __restrict__ out, int Np) {
    __shared__ unsigned short xt[BM * LDST];
    __shared__ float cscale[DHID], cshift[DHID];
    int t = threadIdx.x;
    int lane = t & 63, w = t >> 6;
    long row0 = (long)blockIdx.x * BM;
    if (t < DHID) {
        float invN = 1.f / (float)Np;
        float mu = colsum[t] * invN;
        float ms = gnm[t];
        float var = colsumsq[t] * invN - mu * mu * ms * (2.f - ms);
        float sc = gnw[t] * rsqrtf(var + GN_EPS);
        cscale[t] = sc;
        cshift[t] = (bsum[t] - ms * mu) * sc + gnb[t];
    }
    __syncthreads();
    for (int it = 0; it < 16; ++it) {
        int idx2 = t + it * 256;
        int r = idx2 >> 6, cp = idx2 & 63;
        long gr = row0 + r;
        float v0 = 0.f, v1 = 0.f;
        if (gr < Np) {
            v0 = gat[gr * DHID + 2 * cp] * cscale[2 * cp] + cshift[2 * cp];
            v1 = gat[gr * DHID + 2 * cp + 1] * cscale[2 * cp + 1] + cshift[2 * cp + 1];
        }
        uint32_t pk = (uint32_t)f2bf(v0) | ((uint32_t)f2bf(v1) << 16);
        *reinterpret_cast<uint32_t*>(&xt[r * LDST + 2 * cp]) = pk;
    }
    __syncthreads();
    int arow = w * 16 + (lane & 15);
    int koff = (lane >> 4) << 3;
    short8 af[4];
#pragma unroll
    for (int kk = 0; kk < 4; ++kk)
        af[kk] = *reinterpret_cast<const short8*>(&xt[arow * LDST + kk * 32 + koff]);
    const short8* Bw = reinterpret_cast<const short8*>(W2P);
    int orow = w * 16 + ((lane >> 4) << 2);
    int ccol = lane & 15;
#pragma unroll
    for (int nt = 0; nt < 8; ++nt) {
        f32x4 a = {0.f, 0.f, 0.f, 0.f};
#pragma unroll
        for (int kk = 0; kk < 4; ++kk)
            a = __builtin_amdgcn_mfma_f32_16x16x32_bf16(af[kk], Bw[(nt * 4 + kk) * 64 + lane], a, 0, 0, 0);
        float b = b2[nt * 16 + ccol];
#pragma unroll
        for (int r = 0; r < 4; ++r) {
            long gr = row0 + orow + r;
            if (gr < Np) out[gr * DHID + nt * 16 + ccol] = a[r] + b;
        }
    }
}

// ---------------------------------------------------------------------------
// Author output: gnorm(zeros) == gnb, so every row = gnb@W2_author + b2_author
// ---------------------------------------------------------------------------
__global__ void author_row(const float* __restrict__ gnb_a, const float* __restrict__ W2a,
                           const float* __restrict__ b2a, float* __restrict__ row_a) {
    int t = threadIdx.x;
    float acc = b2a[t];
    for (int k = 0; k < DHID; ++k) acc += gnb_a[k] * W2a[k * DHID + t];
    row_a[t] = acc;
}

__global__ void fill_author(const float* __restrict__ row_a, float* __restrict__ out, long n) {
    long i = (long)blockIdx.x * blockDim.x + threadIdx.x;
    if (i < n) out[i] = row_a[i & (DHID - 1)];
}

// ---------------------------------------------------------------------------
extern "C" void kernel_launch(void* const* d_in, const int* in_sizes, int n_in,
                              void* d_out, int out_size, void* d_ws, size_t ws_size,
                              hipStream_t stream) {
    const float* x_p   = (const float*)d_in[0];
    const float* x_a   = (const float*)d_in[1];
    const int*   e_w   = (const int*)d_in[2];
    const int*   e_c   = (const int*)d_in[3];
    const float* Wlp   = (const float*)d_in[4];
    const float* blp   = (const float*)d_in[5];
    const float* Wla   = (const float*)d_in[6];
    const float* bla   = (const float*)d_in[7];
    const float* Wsw   = (const float*)d_in[8];
    const float* Wdw   = (const float*)d_in[9];
    const float* asw   = (const float*)d_in[10];
    const float* adw   = (const float*)d_in[11];
    const float* bw    = (const float*)d_in[12];
    const float* Wsc   = (const float*)d_in[13];
    const float* Wdc   = (const float*)d_in[14];
    const float* asc   = (const float*)d_in[15];
    const float* adc   = (const float*)d_in[16];
    const float* bc    = (const float*)d_in[17];
    const float* gnw_p = (const float*)d_in[18];
    const float* gnb_p = (const float*)d_in[19];
    const float* gnm_p = (const float*)d_in[20];
    const float* gnb_a = (const float*)d_in[22];
    const float* W2p   = (const float*)d_in[24];
    const float* b2p   = (const float*)d_in[25];
    const float* W2a   = (const float*)d_in[26];
    const float* b2a   = (const float*)d_in[27];

    int Np = in_sizes[0] / DHID;
    int Na = in_sizes[1] / DHID;
    int Ew = in_sizes[2] / 2;
    int Ec = in_sizes[3] / 2;
    int nself_w = Na < Np ? Na : Np;
    int nself_c = Np;
    int tot_w = Ew + nself_w;
    int tot_c = Ec + nself_c;

    float* ws = (float*)d_ws;
    float* gat   = ws;                                 // Np*128
    float* a_s_w = gat + (size_t)Np * DHID;            // Na*8
    float* a_d_w = a_s_w + (size_t)Na * H;             // Np*8
    float* a_s_c = a_d_w + (size_t)Np * H;             // Np*8
    float* a_d_c = a_s_c + (size_t)Np * H;             // Np*8
    float* Vp    = a_d_c + (size_t)Np * H;             // 128*24
    float* Va    = Vp + DHID * 24;                     // 128*8
    float* bsum  = Va + DHID * H;                      // 128
    float* row_a = bsum + DHID;                        // 128
    // ---- zeroed region (one contiguous memset) ----
    float* colsum   = row_a + DHID;                    // 128
    float* colsumsq = colsum + DHID;                   // 128
    int*   degw     = (int*)(colsumsq + DHID);         // Np
    int*   degc     = degw + Np;                       // Np
    size_t zero_bytes = (2 * DHID) * sizeof(float) + 2 * (size_t)Np * sizeof(int);
    // ---- CSR arrays ----
    int* offw  = degc + Np;                            // Np+1
    int* offc  = offw + Np + 1;                        // Np+1
    int* curw  = offc + Np + 1;                        // Np
    int* curc  = curw + Np;                            // Np
    int* srcw  = curc + Np;                            // tot_w
    int* srcc  = srcw + tot_w;                         // tot_c
    int* bs1   = srcc + tot_c;                         // 512
    int* bs2   = bs1 + 512;                            // 512
    // ---- bf16 message arrays ----
    unsigned short* xs_w = (unsigned short*)(bs2 + 512);   // Na*128 bf16
    unsigned short* xs_c = xs_w + (size_t)Na * DHID;       // Np*128 bf16
    // ---- bf16 packed weight fragments (16B-aligned) ----
    uintptr_t up = (uintptr_t)(xs_c + (size_t)Np * DHID);
    up = (up + 15) & ~(uintptr_t)15;
    unsigned short* WlinP_p = (unsigned short*)up;         // 8*4*64*8 = 16384 each
    unsigned short* WsrcP_c = WlinP_p + 16384;
    unsigned short* WlinP_a = WsrcP_c + 16384;
    unsigned short* WsrcP_w = WlinP_a + 16384;
    unsigned short* W2P_p   = WsrcP_w + 16384;
    unsigned short* VscP_p  = W2P_p + 16384;               // 2*4*64*8 = 4096
    unsigned short* VscP_a  = VscP_p + 4096;               // 1*4*64*8 = 2048

    hipMemsetAsync(colsum, 0, zero_bytes, stream);

    fold_kernel<<<4, 128, 0, stream>>>(Wsw, asw, Wdw, adw, Wsc, asc, Wdc, adc,
                                       bw, bc, Vp, Va, bsum);

    // ---- pack weights into MFMA B-fragments ----
    pack_b<<<8, 256, 0, stream>>>(Wlp, DHID, DHID, WlinP_p, 8);
    pack_b<<<8, 256, 0, stream>>>(Wsc, DHID, DHID, WsrcP_c, 8);
    pack_b<<<8, 256, 0, stream>>>(Wla, DHID, DHID, WlinP_a, 8);
    pack_b<<<8, 256, 0, stream>>>(Wsw, DHID, DHID, WsrcP_w, 8);
    pack_b<<<8, 256, 0, stream>>>(W2p, DHID, DHID, W2P_p, 8);
    pack_b<<<2, 256, 0, stream>>>(Vp, 24, 24, VscP_p, 2);
    pack_b<<<1, 256, 0, stream>>>(Va, 8, 8, VscP_a, 1);

    // ---- MFMA projections ----
    proj_mfma<2><<<(Np + BM - 1) / BM, 256, 0, stream>>>(
        x_p, Np, WlinP_p, blp, WsrcP_c, VscP_p, xs_c, a_d_w, a_s_c, a_d_c);
    proj_mfma<1><<<(Na + BM - 1) / BM, 256, 0, stream>>>(
        x_a, Na, WlinP_a, bla, WsrcP_w, VscP_a, xs_w, a_s_w, nullptr, nullptr);

    // ---- CSR build ----
    deg_hist<<<(tot_w + 255) / 256, 256, 0, stream>>>(e_w + Ew, Ew, nself_w, degw);
    deg_hist<<<(tot_c + 255) / 256, 256, 0, stream>>>(e_c + Ec, Ec, nself_c, degc);
    int nb = (Np + SCAN_T * SCAN_I - 1) / (SCAN_T * SCAN_I);
    scan1<<<nb, SCAN_T, 0, stream>>>(degw, Np, offw, bs1);
    scan1<<<nb, SCAN_T, 0, stream>>>(degc, Np, offc, bs2);
    scan1<<<1, SCAN_T, 0, stream>>>(bs1, nb, bs1, bs1 + 480);
    scan1<<<1, SCAN_T, 0, stream>>>(bs2, nb, bs2, bs2 + 480);
    scan3<<<(Np + 256) / 256, 256, 0, stream>>>(offw, bs1, Np, tot_w, curw);
    scan3<<<(Np + 256) / 256, 256, 0, stream>>>(offc, bs2, Np, tot_c, curc);
    csr_scatter<<<(tot_w + 255) / 256, 256, 0, stream>>>(e_w, e_w + Ew, Ew, nself_w, curw, srcw);
    csr_scatter<<<(tot_c + 255) / 256, 256, 0, stream>>>(e_c, e_c + Ec, Ec, nself_c, curc, srcc);

    // ---- fused single-pass gather ----
    gat_gather<<<Np, 128, 0, stream>>>(offw, srcw, offc, srcc,
                                       a_s_w, a_d_w, a_s_c, a_d_c,
                                       xs_w, xs_c, gat, Np);

    gn_reduce<<<(Np + GN_ROWS - 1) / GN_ROWS, 128, 0, stream>>>(gat, bsum, colsum, colsumsq, Np);

    final_mfma<<<(Np + BM - 1) / BM, 256, 0, stream>>>(
        gat, bsum, colsum, colsumsq, gnw_p, gnb_p, gnm_p, W2P_p, b2p, (float*)d_out, Np);

    author_row<<<1, 128, 0, stream>>>(gnb_a, W2a, b2a, row_a);
    {
        long n = (long)Na * DHID;
        fill_author<<<(n + 255) / 256, 256, 0, stream>>>(row_a, (float*)d_out + (size_t)Np * DHID, n);
    }
}

// Round 5
// 374.889 us; speedup vs baseline: 2.0770x; 1.1935x over previous
//
#include <hip/hip_runtime.h>
#include <cstdint>
#include <cstddef>

#define H 8
#define C 16
#define DHID 128
#define BM 64            // rows per MFMA block
#define LDST 136         // padded LDS row stride (bf16 elems): 272B, 16B-aligned, de-conflicts b128 reads
#define NEG_SLOPE 0.2f
#define GN_EPS 1e-5f

#define SCAN_T 256
#define SCAN_I 4       // 1024 elements per scan block

typedef __attribute__((ext_vector_type(8))) short short8;
typedef __attribute__((ext_vector_type(4))) float f32x4;

__device__ __forceinline__ void atomAddF(float* p, float v) {
    __hip_atomic_fetch_add(p, v, __ATOMIC_RELAXED, __HIP_MEMORY_SCOPE_AGENT);
}

__device__ __forceinline__ unsigned short f2bf(float f) {
    uint32_t u = __float_as_uint(f);
    uint32_t r = (u + 0x7FFFu + ((u >> 16) & 1u)) >> 16;
    return (unsigned short)r;
}
__device__ __forceinline__ float bf2f(unsigned short b) {
    return __uint_as_float(((uint32_t)b) << 16);
}
// packed-bf16 pair extract
__device__ __forceinline__ float bflo(uint32_t v) { return __uint_as_float(v << 16); }
__device__ __forceinline__ float bfhi(uint32_t v) { return __uint_as_float(v & 0xFFFF0000u); }

// ---------------------------------------------------------------------------
// Fold attention vectors into combined score matrices:
//   Vp[k][0..7]=Wdst_w@attd_w, [8..15]=Wsrc_c@atts_c, [16..23]=Wdst_c@attd_c
//   Va[k][0..7]=Wsrc_w@atts_w ;  bsum = bias_w + bias_c
// ---------------------------------------------------------------------------
__global__ void fold_kernel(const float* __restrict__ Wsw, const float* __restrict__ asw,
                            const float* __restrict__ Wdw, const float* __restrict__ adw,
                            const float* __restrict__ Wsc, const float* __restrict__ asc,
                            const float* __restrict__ Wdc, const float* __restrict__ adc,
                            const float* __restrict__ bias_w, const float* __restrict__ bias_c,
                            float* __restrict__ Vp, float* __restrict__ Va,
                            float* __restrict__ bsum) {
    int k = threadIdx.x;      // 0..127
    int which = blockIdx.x;   // 0..3
    const float* W = which == 0 ? Wsw : which == 1 ? Wdw : which == 2 ? Wsc : Wdc;
    const float* A = which == 0 ? asw : which == 1 ? adw : which == 2 ? asc : adc;
    for (int h = 0; h < H; ++h) {
        float s = 0.f;
        for (int c = 0; c < C; ++c) s += W[k * DHID + h * C + c] * A[h * C + c];
        if (which == 0) Va[k * H + h] = s;
        else Vp[k * 24 + (which - 1) * H + h] = s;
    }
    if (which == 0) bsum[k] = bias_w[k] + bias_c[k];
}

// ---------------------------------------------------------------------------
// Pack an f32 matrix W[128][ldw] (use cols < ncols, rest zero) into bf16 MFMA
// B-fragments: out[((nt*4+kk)*64+lane)*8+i] = W[kk*32+(lane>>4)*8+i][nt*16+(lane&15)]
// ---------------------------------------------------------------------------
__global__ void pack_b(const float* __restrict__ W, int ldw, int ncols,
                       unsigned short* __restrict__ out, int ntiles) {
    int idx = blockIdx.x * 256 + threadIdx.x;     // one per (nt,kk,lane)
    if (idx >= ntiles * 4 * 64) return;
    int lane = idx & 63, kk = (idx >> 6) & 3, nt = idx >> 8;
    int col = nt * 16 + (lane & 15);
    int k0 = kk * 32 + ((lane >> 4) << 3);
    for (int i = 0; i < 8; ++i)
        out[idx * 8 + i] = (col < ncols) ? f2bf(W[(k0 + i) * ldw + col]) : (unsigned short)0;
}

// ---------------------------------------------------------------------------
// MFMA projection: 256 thr / 4 waves / 64 rows.
//   emb = relu(x@Wlin+b)  (LDS roundtrip, bf16)
//   xs  = emb@Wsrc -> global bf16
//   scores = emb@Vsc -> a0/a1/a2 ([N][8] each); NSC score tiles (2=paper,1=author)
// ---------------------------------------------------------------------------
template <int NSC>
__global__ __launch_bounds__(256) void proj_mfma(
    const float* __restrict__ x, int nrows,
    const unsigned short* __restrict__ WlinP, const float* __restrict__ blin,
    const unsigned short* __restrict__ WsrcP, const unsigned short* __restrict__ VscP,
    unsigned short* __restrict__ xs,
    float* __restrict__ a0, float* __restrict__ a1, float* __restrict__ a2) {
    __shared__ unsigned short xt[BM * LDST];
    int t = threadIdx.x;
    int lane = t & 63, w = t >> 6;
    long row0 = (long)blockIdx.x * BM;
    // ---- stage x tile as bf16 pairs ----
    for (int it = 0; it < 16; ++it) {
        int idx2 = t + it * 256;              // 4096 col-pairs = 64 rows x 64 pairs
        int r = idx2 >> 6, cp = idx2 & 63;
        long gr = row0 + r;
        float v0 = 0.f, v1 = 0.f;
        if (gr < nrows) { v0 = x[gr * DHID + 2 * cp]; v1 = x[gr * DHID + 2 * cp + 1]; }
        uint32_t pk = (uint32_t)f2bf(v0) | ((uint32_t)f2bf(v1) << 16);
        *reinterpret_cast<uint32_t*>(&xt[r * LDST + 2 * cp]) = pk;
    }
    __syncthreads();
    int arow = w * 16 + (lane & 15);          // A-fragment row for this lane
    int koff = (lane >> 4) << 3;              // k sub-offset
    short8 af[4];
#pragma unroll
    for (int kk = 0; kk < 4; ++kk)
        af[kk] = *reinterpret_cast<const short8*>(&xt[arow * LDST + kk * 32 + koff]);
    // ---- GEMM1: emb = x @ Wlin ----
    const short8* Bl = reinterpret_cast<const short8*>(WlinP);
    f32x4 acc[8];
#pragma unroll
    for (int nt = 0; nt < 8; ++nt) {
        f32x4 a = {0.f, 0.f, 0.f, 0.f};
#pragma unroll
        for (int kk = 0; kk < 4; ++kk)
            a = __builtin_amdgcn_mfma_f32_16x16x32_bf16(af[kk], Bl[(nt * 4 + kk) * 64 + lane], a, 0, 0, 0);
        acc[nt] = a;
    }
    __syncthreads();
    // ---- bias + relu, write emb (bf16) back into same LDS tile ----
    int orow = w * 16 + ((lane >> 4) << 2);   // C-layout: row = 4*(lane>>4)+reg
    int ccol = lane & 15;
#pragma unroll
    for (int nt = 0; nt < 8; ++nt) {
        float b = blin[nt * 16 + ccol];
#pragma unroll
        for (int r = 0; r < 4; ++r) {
            float e = fmaxf(acc[nt][r] + b, 0.f);
            xt[(orow + r) * LDST + nt * 16 + ccol] = f2bf(e);
        }
    }
    __syncthreads();
#pragma unroll
    for (int kk = 0; kk < 4; ++kk)
        af[kk] = *reinterpret_cast<const short8*>(&xt[arow * LDST + kk * 32 + koff]);
    // ---- GEMM2: xs = emb @ Wsrc ----
    const short8* Bs = reinterpret_cast<const short8*>(WsrcP);
#pragma unroll
    for (int nt = 0; nt < 8; ++nt) {
        f32x4 a = {0.f, 0.f, 0.f, 0.f};
#pragma unroll
        for (int kk = 0; kk < 4; ++kk)
            a = __builtin_amdgcn_mfma_f32_16x16x32_bf16(af[kk], Bs[(nt * 4 + kk) * 64 + lane], a, 0, 0, 0);
        acc[nt] = a;
    }
    // ---- scores: emb @ Vsc ----
    const short8* Bv = reinterpret_cast<const short8*>(VscP);
    f32x4 sacc0 = {0.f, 0.f, 0.f, 0.f}, sacc1 = {0.f, 0.f, 0.f, 0.f};
#pragma unroll
    for (int kk = 0; kk < 4; ++kk)
        sacc0 = __builtin_amdgcn_mfma_f32_16x16x32_bf16(af[kk], Bv[kk * 64 + lane], sacc0, 0, 0, 0);
    if (NSC > 1) {
#pragma unroll
        for (int kk = 0; kk < 4; ++kk)
            sacc1 = __builtin_amdgcn_mfma_f32_16x16x32_bf16(af[kk], Bv[(4 + kk) * 64 + lane], sacc1, 0, 0, 0);
    }
    // ---- epilogue: xs (bf16) ----
#pragma unroll
    for (int nt = 0; nt < 8; ++nt) {
#pragma unroll
        for (int r = 0; r < 4; ++r) {
            long gr = row0 + orow + r;
            if (gr < nrows) xs[gr * DHID + nt * 16 + ccol] = f2bf(acc[nt][r]);
        }
    }
    // ---- epilogue: scores. packed col -> (which, head): 0-7 a0, 8-15 a1, 16-23 a2 ----
#pragma unroll
    for (int st = 0; st < NSC; ++st) {
        int scol = st * 16 + ccol;
        int h = scol & 7, which = scol >> 3;
        float* ap = which == 0 ? a0 : which == 1 ? a1 : which == 2 ? a2 : nullptr;
        if (ap) {
            f32x4 s = st == 0 ? sacc0 : sacc1;
#pragma unroll
            for (int r = 0; r < 4; ++r) {
                long gr = row0 + orow + r;
                if (gr < nrows) ap[gr * H + h] = s[r];
            }
        }
    }
}

// ---------------------------------------------------------------------------
// CSR build: degree histogram (edges + implicit self-loops)
// ---------------------------------------------------------------------------
__global__ void deg_hist(const int* __restrict__ dst, int E, int nself, int* __restrict__ deg) {
    int i = blockIdx.x * blockDim.x + threadIdx.x;
    if (i < E) atomicAdd(&deg[dst[i]], 1);
    else if (i < E + nself) atomicAdd(&deg[i - E], 1);
}

// Exclusive scan, pass 1: per-block scan + block totals. Safe in-place (out==in).
__global__ void scan1(const int* __restrict__ in, int n, int* __restrict__ out,
                      int* __restrict__ bsums) {
    __shared__ int sh[SCAN_T];
    int t = threadIdx.x;
    long base = (long)blockIdx.x * SCAN_T * SCAN_I;
    int v[SCAN_I];
    int s = 0;
#pragma unroll
    for (int j = 0; j < SCAN_I; ++j) {
        long idx = base + (long)t * SCAN_I + j;
        v[j] = (idx < n) ? in[idx] : 0;
        s += v[j];
    }
    sh[t] = s;
    __syncthreads();
    for (int off = 1; off < SCAN_T; off <<= 1) {
        int x = (t >= off) ? sh[t - off] : 0;
        __syncthreads();
        sh[t] += x;
        __syncthreads();
    }
    int run = sh[t] - s;
#pragma unroll
    for (int j = 0; j < SCAN_I; ++j) {
        long idx = base + (long)t * SCAN_I + j;
        if (idx < n) out[idx] = run;
        run += v[j];
    }
    if (t == SCAN_T - 1) bsums[blockIdx.x] = sh[SCAN_T - 1];
}

// pass 3: add block offsets, write sentinel, init cursors
__global__ void scan3(int* __restrict__ off, const int* __restrict__ bsums, int n, int total,
                      int* __restrict__ cur) {
    int i = blockIdx.x * blockDim.x + threadIdx.x;
    if (i < n) {
        int v = off[i] + bsums[i / (SCAN_T * SCAN_I)];
        off[i] = v;
        cur[i] = v;
    }
    if (i == n) off[n] = total;
}

// scatter: fill per-dst src lists using atomic cursors
__global__ void csr_scatter(const int* __restrict__ src, const int* __restrict__ dst,
                            int E, int nself, int* __restrict__ cur, int* __restrict__ srcarr) {
    int i = blockIdx.x * blockDim.x + threadIdx.x;
    if (i >= E + nself) return;
    int s, d;
    if (i < E) { s = src[i]; d = dst[i]; } else { s = d = i - E; }
    int pos = atomicAdd(&cur[d], 1);
    srcarr[pos] = s;
}

// ---------------------------------------------------------------------------
// One edge-type segment gather, 64 lanes per dst, lane owns cols {2l, 2l+1}.
// Unrolled x4: 4 src ids -> 4 score + 4 row loads in flight (MLP) -> combine.
// Returns (num0,num1)/den.
// ---------------------------------------------------------------------------
__device__ __forceinline__ float2 seg_gather(const int* __restrict__ off,
                                             const int* __restrict__ srcarr,
                                             const float* __restrict__ a_s,
                                             const float* __restrict__ a_d,
                                             const unsigned short* __restrict__ xs,
                                             int d, int l, int h) {
    int b0 = off[d], b1 = off[d + 1];
    float ad = a_d[(long)d * H + h];
    float den = 0.f, n0 = 0.f, n1 = 0.f;
    int i = b0;
    for (; i + 4 <= b1; i += 4) {
        int s0 = srcarr[i], s1 = srcarr[i + 1], s2 = srcarr[i + 2], s3 = srcarr[i + 3];
        float e0 = a_s[(long)s0 * H + h];
        float e1 = a_s[(long)s1 * H + h];
        float e2 = a_s[(long)s2 * H + h];
        float e3 = a_s[(long)s3 * H + h];
        uint32_t v0 = *reinterpret_cast<const uint32_t*>(xs + (long)s0 * DHID + 2 * l);
        uint32_t v1 = *reinterpret_cast<const uint32_t*>(xs + (long)s1 * DHID + 2 * l);
        uint32_t v2 = *reinterpret_cast<const uint32_t*>(xs + (long)s2 * DHID + 2 * l);
        uint32_t v3 = *reinterpret_cast<const uint32_t*>(xs + (long)s3 * DHID + 2 * l);
        e0 += ad; e0 = e0 > 0.f ? e0 : NEG_SLOPE * e0; float p0 = __expf(e0);
        e1 += ad; e1 = e1 > 0.f ? e1 : NEG_SLOPE * e1; float p1 = __expf(e1);
        e2 += ad; e2 = e2 > 0.f ? e2 : NEG_SLOPE * e2; float p2 = __expf(e2);
        e3 += ad; e3 = e3 > 0.f ? e3 : NEG_SLOPE * e3; float p3 = __expf(e3);
        den += (p0 + p1) + (p2 + p3);
        n0 += p0 * bflo(v0) + p1 * bflo(v1) + p2 * bflo(v2) + p3 * bflo(v3);
        n1 += p0 * bfhi(v0) + p1 * bfhi(v1) + p2 * bfhi(v2) + p3 * bfhi(v3);
    }
    for (; i < b1; ++i) {
        int s = srcarr[i];
        float e = a_s[(long)s * H + h] + ad;
        e = e > 0.f ? e : NEG_SLOPE * e;
        float p = __expf(e);
        uint32_t v = *reinterpret_cast<const uint32_t*>(xs + (long)s * DHID + 2 * l);
        den += p;
        n0 += p * bflo(v);
        n1 += p * bfhi(v);
    }
    float r = 1.f / (den + 1e-16f);
    float2 o; o.x = n0 * r; o.y = n1 * r;
    return o;
}

// 256 threads = 4 papers x 64 lanes.
__global__ __launch_bounds__(256) void gat_gather(
    const int* __restrict__ offw, const int* __restrict__ srcw,
    const int* __restrict__ offc, const int* __restrict__ srcc,
    const float* __restrict__ a_s_w, const float* __restrict__ a_d_w,
    const float* __restrict__ a_s_c, const float* __restrict__ a_d_c,
    const unsigned short* __restrict__ xs_w, const unsigned short* __restrict__ xs_c,
    float* __restrict__ gat, int Np) {
    int l = threadIdx.x & 63;
    int d = blockIdx.x * 4 + (threadIdx.x >> 6);
    if (d >= Np) return;
    int h = l >> 3;
    float2 ow = seg_gather(offw, srcw, a_s_w, a_d_w, xs_w, d, l, h);
    float2 oc = seg_gather(offc, srcc, a_s_c, a_d_c, xs_c, d, l, h);
    float2 o; o.x = ow.x + oc.x; o.y = ow.y + oc.y;
    *reinterpret_cast<float2*>(&gat[(long)d * DHID + 2 * l]) = o;
}

// ---------------------------------------------------------------------------
// GraphNorm reduction: per-column sum and sum-of-squares of (gat + bsum)
// ---------------------------------------------------------------------------
#define GN_ROWS 128
__global__ void gn_reduce(const float* __restrict__ gat, const float* __restrict__ bsum,
                          float* __restrict__ colsum, float* __restrict__ colsumsq, int Np) {
    int t = threadIdx.x;
    long r0 = (long)blockIdx.x * GN_ROWS;
    long r1 = min(r0 + GN_ROWS, (long)Np);
    float b = bsum[t], s1 = 0.f, s2 = 0.f;
    for (long r = r0; r < r1; ++r) {
        float xv = gat[r * DHID + t] + b;
        s1 += xv;
        s2 += xv * xv;
    }
    atomAddF(colsum + t, s1);
    atomAddF(colsumsq + t, s2);
}

// ---------------------------------------------------------------------------
// Final paper via MFMA: nrm = (gat+bsum)*cscale + cshift (bf16 in LDS), @W2 + b2.
// ---------------------------------------------------------------------------
__global__ __launch_bounds__(256) void final_mfma(
    const float* __restrict__ gat, const float* __restrict__ bsum,
    const float* __restrict__ colsum, const float* __restrict__ colsumsq,
    const float* __restrict__ gnw, const float* __restrict__ gnb,
    const float* __restrict__ gnm,
    const unsigned short* __restrict__ W2P, const float* __restrict__ b2,
    float* __restrict__ out, int Np) {
    __shared__ unsigned short xt[BM * LDST];
    __shared__ float cscale[DHID], cshift[DHID];
    int t = threadIdx.x;
    int lane = t & 63, w = t >> 6;
    long row0 = (long)blockIdx.x * BM;
    if (t < DHID) {
        float invN = 1.f / (float)Np;
        float mu = colsum[t] * invN;
        float ms = gnm[t];
        float var = colsumsq[t] * invN - mu * mu * ms * (2.f - ms);
        float sc = gnw[t] * rsqrtf(var + GN_EPS);
        cscale[t] = sc;
        cshift[t] = (bsum[t] - ms * mu) * sc + gnb[t];
    }
    __syncthreads();
    for (int it = 0; it < 16; ++it) {
        int idx2 = t + it * 256;
        int r = idx2 >> 6, cp = idx2 & 63;
        long gr = row0 + r;
        float v0 = 0.f, v1 = 0.f;
        if (gr < Np) {
            v0 = gat[gr * DHID + 2 * cp] * cscale[2 * cp] + cshift[2 * cp];
            v1 = gat[gr * DHID + 2 * cp + 1] * cscale[2 * cp + 1] + cshift[2 * cp + 1];
        }
        uint32_t pk = (uint32_t)f2bf(v0) | ((uint32_t)f2bf(v1) << 16);
        *reinterpret_cast<uint32_t*>(&xt[r * LDST + 2 * cp]) = pk;
    }
    __syncthreads();
    int arow = w * 16 + (lane & 15);
    int koff = (lane >> 4) << 3;
    short8 af[4];
#pragma unroll
    for (int kk = 0; kk < 4; ++kk)
        af[kk] = *reinterpret_cast<const short8*>(&xt[arow * LDST + kk * 32 + koff]);
    const short8* Bw = reinterpret_cast<const short8*>(W2P);
    int orow = w * 16 + ((lane >> 4) << 2);
    int ccol = lane & 15;
#pragma unroll
    for (int nt = 0; nt < 8; ++nt) {
        f32x4 a = {0.f, 0.f, 0.f, 0.f};
#pragma unroll
        for (int kk = 0; kk < 4; ++kk)
            a = __builtin_amdgcn_mfma_f32_16x16x32_bf16(af[kk], Bw[(nt * 4 + kk) * 64 + lane], a, 0, 0, 0);
        float b = b2[nt * 16 + ccol];
#pragma unroll
        for (int r = 0; r < 4; ++r) {
            long gr = row0 + orow + r;
            if (gr < Np) out[gr * DHID + nt * 16 + ccol] = a[r] + b;
        }
    }
}

// ---------------------------------------------------------------------------
// Author output: gnorm(zeros) == gnb, so every row = gnb@W2_author + b2_author
// ---------------------------------------------------------------------------
__global__ void author_row(const float* __restrict__ gnb_a, const float* __restrict__ W2a,
                           const float* __restrict__ b2a, float* __restrict__ row_a) {
    int t = threadIdx.x;
    float acc = b2a[t];
    for (int k = 0; k < DHID; ++k) acc += gnb_a[k] * W2a[k * DHID + t];
    row_a[t] = acc;
}

__global__ void fill_author(const float* __restrict__ row_a, float* __restrict__ out, long n) {
    long i = (long)blockIdx.x * blockDim.x + threadIdx.x;
    if (i < n) out[i] = row_a[i & (DHID - 1)];
}

// ---------------------------------------------------------------------------
extern "C" void kernel_launch(void* const* d_in, const int* in_sizes, int n_in,
                              void* d_out, int out_size, void* d_ws, size_t ws_size,
                              hipStream_t stream) {
    const float* x_p   = (const float*)d_in[0];
    const float* x_a   = (const float*)d_in[1];
    const int*   e_w   = (const int*)d_in[2];
    const int*   e_c   = (const int*)d_in[3];
    const float* Wlp   = (const float*)d_in[4];
    const float* blp   = (const float*)d_in[5];
    const float* Wla   = (const float*)d_in[6];
    const float* bla   = (const float*)d_in[7];
    const float* Wsw   = (const float*)d_in[8];
    const float* Wdw   = (const float*)d_in[9];
    const float* asw   = (const float*)d_in[10];
    const float* adw   = (const float*)d_in[11];
    const float* bw    = (const float*)d_in[12];
    const float* Wsc   = (const float*)d_in[13];
    const float* Wdc   = (const float*)d_in[14];
    const float* asc   = (const float*)d_in[15];
    const float* adc   = (const float*)d_in[16];
    const float* bc    = (const float*)d_in[17];
    const float* gnw_p = (const float*)d_in[18];
    const float* gnb_p = (const float*)d_in[19];
    const float* gnm_p = (const float*)d_in[20];
    const float* gnb_a = (const float*)d_in[22];
    const float* W2p   = (const float*)d_in[24];
    const float* b2p   = (const float*)d_in[25];
    const float* W2a   = (const float*)d_in[26];
    const float* b2a   = (const float*)d_in[27];

    int Np = in_sizes[0] / DHID;
    int Na = in_sizes[1] / DHID;
    int Ew = in_sizes[2] / 2;
    int Ec = in_sizes[3] / 2;
    int nself_w = Na < Np ? Na : Np;
    int nself_c = Np;
    int tot_w = Ew + nself_w;
    int tot_c = Ec + nself_c;

    float* ws = (float*)d_ws;
    float* gat   = ws;                                 // Np*128
    float* a_s_w = gat + (size_t)Np * DHID;            // Na*8
    float* a_d_w = a_s_w + (size_t)Na * H;             // Np*8
    float* a_s_c = a_d_w + (size_t)Np * H;             // Np*8
    float* a_d_c = a_s_c + (size_t)Np * H;             // Np*8
    float* Vp    = a_d_c + (size_t)Np * H;             // 128*24
    float* Va    = Vp + DHID * 24;                     // 128*8
    float* bsum  = Va + DHID * H;                      // 128
    float* row_a = bsum + DHID;                        // 128
    // ---- zeroed region (one contiguous memset) ----
    float* colsum   = row_a + DHID;                    // 128
    float* colsumsq = colsum + DHID;                   // 128
    int*   degw     = (int*)(colsumsq + DHID);         // Np
    int*   degc     = degw + Np;                       // Np
    size_t zero_bytes = (2 * DHID) * sizeof(float) + 2 * (size_t)Np * sizeof(int);
    // ---- CSR arrays ----
    int* offw  = degc + Np;                            // Np+1
    int* offc  = offw + Np + 1;                        // Np+1
    int* curw  = offc + Np + 1;                        // Np
    int* curc  = curw + Np;                            // Np
    int* srcw  = curc + Np;                            // tot_w
    int* srcc  = srcw + tot_w;                         // tot_c
    int* bs1   = srcc + tot_c;                         // 512
    int* bs2   = bs1 + 512;                            // 512
    // ---- bf16 message arrays ----
    unsigned short* xs_w = (unsigned short*)(bs2 + 512);   // Na*128 bf16
    unsigned short* xs_c = xs_w + (size_t)Na * DHID;       // Np*128 bf16
    // ---- bf16 packed weight fragments (16B-aligned) ----
    uintptr_t up = (uintptr_t)(xs_c + (size_t)Np * DHID);
    up = (up + 15) & ~(uintptr_t)15;
    unsigned short* WlinP_p = (unsigned short*)up;         // 8*4*64*8 = 16384 each
    unsigned short* WsrcP_c = WlinP_p + 16384;
    unsigned short* WlinP_a = WsrcP_c + 16384;
    unsigned short* WsrcP_w = WlinP_a + 16384;
    unsigned short* W2P_p   = WsrcP_w + 16384;
    unsigned short* VscP_p  = W2P_p + 16384;               // 2*4*64*8 = 4096
    unsigned short* VscP_a  = VscP_p + 4096;               // 1*4*64*8 = 2048

    hipMemsetAsync(colsum, 0, zero_bytes, stream);

    fold_kernel<<<4, 128, 0, stream>>>(Wsw, asw, Wdw, adw, Wsc, asc, Wdc, adc,
                                       bw, bc, Vp, Va, bsum);

    // ---- pack weights into MFMA B-fragments ----
    pack_b<<<8, 256, 0, stream>>>(Wlp, DHID, DHID, WlinP_p, 8);
    pack_b<<<8, 256, 0, stream>>>(Wsc, DHID, DHID, WsrcP_c, 8);
    pack_b<<<8, 256, 0, stream>>>(Wla, DHID, DHID, WlinP_a, 8);
    pack_b<<<8, 256, 0, stream>>>(Wsw, DHID, DHID, WsrcP_w, 8);
    pack_b<<<8, 256, 0, stream>>>(W2p, DHID, DHID, W2P_p, 8);
    pack_b<<<2, 256, 0, stream>>>(Vp, 24, 24, VscP_p, 2);
    pack_b<<<1, 256, 0, stream>>>(Va, 8, 8, VscP_a, 1);

    // ---- MFMA projections ----
    proj_mfma<2><<<(Np + BM - 1) / BM, 256, 0, stream>>>(
        x_p, Np, WlinP_p, blp, WsrcP_c, VscP_p, xs_c, a_d_w, a_s_c, a_d_c);
    proj_mfma<1><<<(Na + BM - 1) / BM, 256, 0, stream>>>(
        x_a, Na, WlinP_a, bla, WsrcP_w, VscP_a, xs_w, a_s_w, nullptr, nullptr);

    // ---- CSR build ----
    deg_hist<<<(tot_w + 255) / 256, 256, 0, stream>>>(e_w + Ew, Ew, nself_w, degw);
    deg_hist<<<(tot_c + 255) / 256, 256, 0, stream>>>(e_c + Ec, Ec, nself_c, degc);
    int nb = (Np + SCAN_T * SCAN_I - 1) / (SCAN_T * SCAN_I);
    scan1<<<nb, SCAN_T, 0, stream>>>(degw, Np, offw, bs1);
    scan1<<<nb, SCAN_T, 0, stream>>>(degc, Np, offc, bs2);
    scan1<<<1, SCAN_T, 0, stream>>>(bs1, nb, bs1, bs1 + 480);
    scan1<<<1, SCAN_T, 0, stream>>>(bs2, nb, bs2, bs2 + 480);
    scan3<<<(Np + 256) / 256, 256, 0, stream>>>(offw, bs1, Np, tot_w, curw);
    scan3<<<(Np + 256) / 256, 256, 0, stream>>>(offc, bs2, Np, tot_c, curc);
    csr_scatter<<<(tot_w + 255) / 256, 256, 0, stream>>>(e_w, e_w + Ew, Ew, nself_w, curw, srcw);
    csr_scatter<<<(tot_c + 255) / 256, 256, 0, stream>>>(e_c, e_c + Ec, Ec, nself_c, curc, srcc);

    // ---- fused single-pass gather (4 papers/block, 64 lanes each, unroll-4 MLP) ----
    gat_gather<<<(Np + 3) / 4, 256, 0, stream>>>(offw, srcw, offc, srcc,
                                                 a_s_w, a_d_w, a_s_c, a_d_c,
                                                 xs_w, xs_c, gat, Np);

    gn_reduce<<<(Np + GN_ROWS - 1) / GN_ROWS, 128, 0, stream>>>(gat, bsum, colsum, colsumsq, Np);

    final_mfma<<<(Np + BM - 1) / BM, 256, 0, stream>>>(
        gat, bsum, colsum, colsumsq, gnw_p, gnb_p, gnm_p, W2P_p, b2p, (float*)d_out, Np);

    author_row<<<1, 128, 0, stream>>>(gnb_a, W2a, b2a, row_a);
    {
        long n = (long)Na * DHID;
        fill_author<<<(n + 255) / 256, 256, 0, stream>>>(row_a, (float*)d_out + (size_t)Np * DHID, n);
    }
}

// Round 6
// 367.539 us; speedup vs baseline: 2.1186x; 1.0200x over previous
//
#include <hip/hip_runtime.h>
#include <cstdint>
#include <cstddef>

#define H 8
#define C 16
#define DHID 128
#define BM 64            // rows per MFMA block
#define LDST 136         // padded LDS row stride (bf16 elems)
#define NEG_SLOPE 0.2f
#define GN_EPS 1e-5f

#define SCAN_T 256
#define SCAN_I 4       // 1024 elements per scan block

typedef __attribute__((ext_vector_type(8))) short short8;
typedef __attribute__((ext_vector_type(4))) float f32x4;

__device__ __forceinline__ void atomAddF(float* p, float v) {
    __hip_atomic_fetch_add(p, v, __ATOMIC_RELAXED, __HIP_MEMORY_SCOPE_AGENT);
}

__device__ __forceinline__ unsigned short f2bf(float f) {
    uint32_t u = __float_as_uint(f);
    uint32_t r = (u + 0x7FFFu + ((u >> 16) & 1u)) >> 16;
    return (unsigned short)r;
}
// packed-bf16 pair extract
__device__ __forceinline__ float bflo(uint32_t v) { return __uint_as_float(v << 16); }
__device__ __forceinline__ float bfhi(uint32_t v) { return __uint_as_float(v & 0xFFFF0000u); }

// ---------------------------------------------------------------------------
// Fold attention vectors into combined score matrices:
//   Vp[k][0..7]=Wdst_w@attd_w, [8..15]=Wsrc_c@atts_c, [16..23]=Wdst_c@attd_c
//   Va[k][0..7]=Wsrc_w@atts_w ;  bsum = bias_w + bias_c
// ---------------------------------------------------------------------------
__global__ void fold_kernel(const float* __restrict__ Wsw, const float* __restrict__ asw,
                            const float* __restrict__ Wdw, const float* __restrict__ adw,
                            const float* __restrict__ Wsc, const float* __restrict__ asc,
                            const float* __restrict__ Wdc, const float* __restrict__ adc,
                            const float* __restrict__ bias_w, const float* __restrict__ bias_c,
                            float* __restrict__ Vp, float* __restrict__ Va,
                            float* __restrict__ bsum) {
    int k = threadIdx.x;      // 0..127
    int which = blockIdx.x;   // 0..3
    const float* W = which == 0 ? Wsw : which == 1 ? Wdw : which == 2 ? Wsc : Wdc;
    const float* A = which == 0 ? asw : which == 1 ? adw : which == 2 ? asc : adc;
    for (int h = 0; h < H; ++h) {
        float s = 0.f;
        for (int c = 0; c < C; ++c) s += W[k * DHID + h * C + c] * A[h * C + c];
        if (which == 0) Va[k * H + h] = s;
        else Vp[k * 24 + (which - 1) * H + h] = s;
    }
    if (which == 0) bsum[k] = bias_w[k] + bias_c[k];
}

// ---------------------------------------------------------------------------
// Pack f32 matrices into bf16 MFMA B-fragments, all 7 jobs in one launch.
// out[((nt*4+kk)*64+lane)*8+i] = W[kk*32+(lane>>4)*8+i][nt*16+(lane&15)]
// ---------------------------------------------------------------------------
struct PackArgs {
    const float* W[7];
    unsigned short* out[7];
    int ldw[7], ncols[7], ntiles[7];
};
__global__ void pack_all(PackArgs pa) {
    int j = blockIdx.y;
    int idx = blockIdx.x * 256 + threadIdx.x;     // one per (nt,kk,lane)
    if (idx >= pa.ntiles[j] * 256) return;
    int lane = idx & 63, kk = (idx >> 6) & 3, nt = idx >> 8;
    int col = nt * 16 + (lane & 15);
    int k0 = kk * 32 + ((lane >> 4) << 3);
    const float* W = pa.W[j];
    unsigned short* out = pa.out[j];
    int ldw = pa.ldw[j], ncols = pa.ncols[j];
    for (int i = 0; i < 8; ++i)
        out[idx * 8 + i] = (col < ncols) ? f2bf(W[(k0 + i) * ldw + col]) : (unsigned short)0;
}

// ---------------------------------------------------------------------------
// MFMA projection: 256 thr / 4 waves / 64 rows. (unchanged from round 5)
// ---------------------------------------------------------------------------
template <int NSC>
__global__ __launch_bounds__(256) void proj_mfma(
    const float* __restrict__ x, int nrows,
    const unsigned short* __restrict__ WlinP, const float* __restrict__ blin,
    const unsigned short* __restrict__ WsrcP, const unsigned short* __restrict__ VscP,
    unsigned short* __restrict__ xs,
    float* __restrict__ a0, float* __restrict__ a1, float* __restrict__ a2) {
    __shared__ unsigned short xt[BM * LDST];
    int t = threadIdx.x;
    int lane = t & 63, w = t >> 6;
    long row0 = (long)blockIdx.x * BM;
    for (int it = 0; it < 16; ++it) {
        int idx2 = t + it * 256;
        int r = idx2 >> 6, cp = idx2 & 63;
        long gr = row0 + r;
        float v0 = 0.f, v1 = 0.f;
        if (gr < nrows) { v0 = x[gr * DHID + 2 * cp]; v1 = x[gr * DHID + 2 * cp + 1]; }
        uint32_t pk = (uint32_t)f2bf(v0) | ((uint32_t)f2bf(v1) << 16);
        *reinterpret_cast<uint32_t*>(&xt[r * LDST + 2 * cp]) = pk;
    }
    __syncthreads();
    int arow = w * 16 + (lane & 15);
    int koff = (lane >> 4) << 3;
    short8 af[4];
#pragma unroll
    for (int kk = 0; kk < 4; ++kk)
        af[kk] = *reinterpret_cast<const short8*>(&xt[arow * LDST + kk * 32 + koff]);
    const short8* Bl = reinterpret_cast<const short8*>(WlinP);
    f32x4 acc[8];
#pragma unroll
    for (int nt = 0; nt < 8; ++nt) {
        f32x4 a = {0.f, 0.f, 0.f, 0.f};
#pragma unroll
        for (int kk = 0; kk < 4; ++kk)
            a = __builtin_amdgcn_mfma_f32_16x16x32_bf16(af[kk], Bl[(nt * 4 + kk) * 64 + lane], a, 0, 0, 0);
        acc[nt] = a;
    }
    __syncthreads();
    int orow = w * 16 + ((lane >> 4) << 2);
    int ccol = lane & 15;
#pragma unroll
    for (int nt = 0; nt < 8; ++nt) {
        float b = blin[nt * 16 + ccol];
#pragma unroll
        for (int r = 0; r < 4; ++r) {
            float e = fmaxf(acc[nt][r] + b, 0.f);
            xt[(orow + r) * LDST + nt * 16 + ccol] = f2bf(e);
        }
    }
    __syncthreads();
#pragma unroll
    for (int kk = 0; kk < 4; ++kk)
        af[kk] = *reinterpret_cast<const short8*>(&xt[arow * LDST + kk * 32 + koff]);
    const short8* Bs = reinterpret_cast<const short8*>(WsrcP);
#pragma unroll
    for (int nt = 0; nt < 8; ++nt) {
        f32x4 a = {0.f, 0.f, 0.f, 0.f};
#pragma unroll
        for (int kk = 0; kk < 4; ++kk)
            a = __builtin_amdgcn_mfma_f32_16x16x32_bf16(af[kk], Bs[(nt * 4 + kk) * 64 + lane], a, 0, 0, 0);
        acc[nt] = a;
    }
    const short8* Bv = reinterpret_cast<const short8*>(VscP);
    f32x4 sacc0 = {0.f, 0.f, 0.f, 0.f}, sacc1 = {0.f, 0.f, 0.f, 0.f};
#pragma unroll
    for (int kk = 0; kk < 4; ++kk)
        sacc0 = __builtin_amdgcn_mfma_f32_16x16x32_bf16(af[kk], Bv[kk * 64 + lane], sacc0, 0, 0, 0);
    if (NSC > 1) {
#pragma unroll
        for (int kk = 0; kk < 4; ++kk)
            sacc1 = __builtin_amdgcn_mfma_f32_16x16x32_bf16(af[kk], Bv[(4 + kk) * 64 + lane], sacc1, 0, 0, 0);
    }
#pragma unroll
    for (int nt = 0; nt < 8; ++nt) {
#pragma unroll
        for (int r = 0; r < 4; ++r) {
            long gr = row0 + orow + r;
            if (gr < nrows) xs[gr * DHID + nt * 16 + ccol] = f2bf(acc[nt][r]);
        }
    }
#pragma unroll
    for (int st = 0; st < NSC; ++st) {
        int scol = st * 16 + ccol;
        int h = scol & 7, which = scol >> 3;
        float* ap = which == 0 ? a0 : which == 1 ? a1 : which == 2 ? a2 : nullptr;
        if (ap) {
            f32x4 s = st == 0 ? sacc0 : sacc1;
#pragma unroll
            for (int r = 0; r < 4; ++r) {
                long gr = row0 + orow + r;
                if (gr < nrows) ap[gr * H + h] = s[r];
            }
        }
    }
}

// ---------------------------------------------------------------------------
// Unified CSR degree histogram over both edge types (+ self loops), also
// initializes the phantom rows (xs=0, a_s=-1e30) used for segment padding.
// deg has 2*Np slots: [0,Np) writes-type, [Np,2Np) cites-type.
// ---------------------------------------------------------------------------
__global__ void deg_hist(const int* __restrict__ dst_w, int Ew, int nself_w,
                         const int* __restrict__ dst_c, int Ec, int nself_c,
                         int Np, int* __restrict__ deg,
                         unsigned short* __restrict__ xs_w_ph, float* __restrict__ as_w_ph,
                         unsigned short* __restrict__ xs_c_ph, float* __restrict__ as_c_ph) {
    int i = blockIdx.x * 256 + threadIdx.x;
    if (blockIdx.x == 0) {
        int t = threadIdx.x;
        if (t < 128) { xs_w_ph[t] = 0; xs_c_ph[t] = 0; }
        else if (t < 136) as_w_ph[t - 128] = -1e30f;
        else if (t < 144) as_c_ph[t - 136] = -1e30f;
    }
    int tot_w = Ew + nself_w;
    if (i < tot_w) {
        int d = (i < Ew) ? dst_w[i] : (i - Ew);
        atomicAdd(&deg[d], 1);
    } else if (i < tot_w + Ec + nself_c) {
        int j = i - tot_w;
        int d = (j < Ec) ? dst_c[j] : (j - Ec);
        atomicAdd(&deg[Np + d], 1);
    }
}

// Exclusive scan, pass 1. pad!=0 rounds each value up to a multiple of 4.
// totalOut (if non-null) receives the inclusive grand total (single-block use).
__global__ void scan1(const int* __restrict__ in, int n, int* __restrict__ out,
                      int* __restrict__ bsums, int pad, int* __restrict__ totalOut) {
    __shared__ int sh[SCAN_T];
    int t = threadIdx.x;
    long base = (long)blockIdx.x * SCAN_T * SCAN_I;
    int v[SCAN_I];
    int s = 0;
#pragma unroll
    for (int j = 0; j < SCAN_I; ++j) {
        long idx = base + (long)t * SCAN_I + j;
        int x = (idx < n) ? in[idx] : 0;
        if (pad) x = (x + 3) & ~3;
        v[j] = x;
        s += x;
    }
    sh[t] = s;
    __syncthreads();
    for (int off = 1; off < SCAN_T; off <<= 1) {
        int x = (t >= off) ? sh[t - off] : 0;
        __syncthreads();
        sh[t] += x;
        __syncthreads();
    }
    int run = sh[t] - s;
#pragma unroll
    for (int j = 0; j < SCAN_I; ++j) {
        long idx = base + (long)t * SCAN_I + j;
        if (idx < n) out[idx] = run;
        run += v[j];
    }
    if (t == SCAN_T - 1) {
        bsums[blockIdx.x] = sh[SCAN_T - 1];
        if (totalOut) *totalOut = sh[SCAN_T - 1];
    }
}

// pass 3: add block offsets, init cursors
__global__ void scan3(int* __restrict__ off, const int* __restrict__ bsums, int n,
                      int* __restrict__ cur) {
    int i = blockIdx.x * blockDim.x + threadIdx.x;
    if (i < n) {
        int v = off[i] + bsums[i / (SCAN_T * SCAN_I)];
        off[i] = v;
        cur[i] = v;
    }
}

// prefill padded src array with phantom indices (Na for w-region, Np for c-region)
__global__ void prefill(const int* __restrict__ off, int Np, int Na, int* __restrict__ srcu) {
    int i = blockIdx.x * 256 + threadIdx.x;
    int mid = off[Np], end = off[2 * Np];
    if (i < end) srcu[i] = (i < mid) ? Na : Np;
}

// unified scatter: fill per-dst src lists using atomic cursors
__global__ void csr_scatter(const int* __restrict__ src_w, const int* __restrict__ dst_w,
                            int Ew, int nself_w,
                            const int* __restrict__ src_c, const int* __restrict__ dst_c,
                            int Ec, int nself_c, int Np,
                            int* __restrict__ cur, int* __restrict__ srcu) {
    int i = blockIdx.x * 256 + threadIdx.x;
    int tot_w = Ew + nself_w;
    int s, di;
    if (i < tot_w) {
        if (i < Ew) { s = src_w[i]; di = dst_w[i]; } else { s = di = i - Ew; }
    } else if (i < tot_w + Ec + nself_c) {
        int j = i - tot_w;
        if (j < Ec) { s = src_c[j]; di = Np + dst_c[j]; }
        else { s = j - Ec; di = Np + (j - Ec); }
    } else return;
    int pos = atomicAdd(&cur[di], 1);
    srcu[pos] = s;
}

// ---------------------------------------------------------------------------
// Gather: 64 lanes per paper (lane owns cols 2l,2l+1), 4 papers per 256-block.
// Both edge types interleaved per iteration: 2x int4 ids + 8 score loads +
// 8 row loads in flight. Segments padded to x4 with exact-zero phantoms.
// ---------------------------------------------------------------------------
__global__ __launch_bounds__(256) void gat_gather(
    const int* __restrict__ off, const int* __restrict__ srcu,
    const float* __restrict__ a_s_w, const float* __restrict__ a_d_w,
    const float* __restrict__ a_s_c, const float* __restrict__ a_d_c,
    const unsigned short* __restrict__ xs_w, const unsigned short* __restrict__ xs_c,
    float* __restrict__ gat, int Np) {
    int l = threadIdx.x & 63;
    int d = blockIdx.x * 4 + (threadIdx.x >> 6);
    if (d >= Np) return;
    int h = l >> 3;
    int iw = off[d], w1 = off[d + 1];
    int ic = off[Np + d], c1 = off[Np + d + 1];
    float adw = a_d_w[(long)d * H + h];
    float adc = a_d_c[(long)d * H + h];
    float denw = 0.f, n0w = 0.f, n1w = 0.f;
    float denc = 0.f, n0c = 0.f, n1c = 0.f;
    while (iw < w1 || ic < c1) {
        bool hw = iw < w1, hc = ic < c1;
        int4 sw, sc;
        if (hw) sw = *reinterpret_cast<const int4*>(srcu + iw);
        if (hc) sc = *reinterpret_cast<const int4*>(srcu + ic);
        float ew[4], ec[4];
        uint32_t vw[4], vc[4];
        if (hw) {
            ew[0] = a_s_w[(long)sw.x * H + h];
            ew[1] = a_s_w[(long)sw.y * H + h];
            ew[2] = a_s_w[(long)sw.z * H + h];
            ew[3] = a_s_w[(long)sw.w * H + h];
            vw[0] = *reinterpret_cast<const uint32_t*>(xs_w + (long)sw.x * DHID + 2 * l);
            vw[1] = *reinterpret_cast<const uint32_t*>(xs_w + (long)sw.y * DHID + 2 * l);
            vw[2] = *reinterpret_cast<const uint32_t*>(xs_w + (long)sw.z * DHID + 2 * l);
            vw[3] = *reinterpret_cast<const uint32_t*>(xs_w + (long)sw.w * DHID + 2 * l);
        }
        if (hc) {
            ec[0] = a_s_c[(long)sc.x * H + h];
            ec[1] = a_s_c[(long)sc.y * H + h];
            ec[2] = a_s_c[(long)sc.z * H + h];
            ec[3] = a_s_c[(long)sc.w * H + h];
            vc[0] = *reinterpret_cast<const uint32_t*>(xs_c + (long)sc.x * DHID + 2 * l);
            vc[1] = *reinterpret_cast<const uint32_t*>(xs_c + (long)sc.y * DHID + 2 * l);
            vc[2] = *reinterpret_cast<const uint32_t*>(xs_c + (long)sc.z * DHID + 2 * l);
            vc[3] = *reinterpret_cast<const uint32_t*>(xs_c + (long)sc.w * DHID + 2 * l);
        }
        if (hw) {
#pragma unroll
            for (int j = 0; j < 4; ++j) {
                float e = ew[j] + adw;
                e = e > 0.f ? e : NEG_SLOPE * e;
                float p = __expf(e);
                denw += p;
                n0w += p * bflo(vw[j]);
                n1w += p * bfhi(vw[j]);
            }
            iw += 4;
        }
        if (hc) {
#pragma unroll
            for (int j = 0; j < 4; ++j) {
                float e = ec[j] + adc;
                e = e > 0.f ? e : NEG_SLOPE * e;
                float p = __expf(e);
                denc += p;
                n0c += p * bflo(vc[j]);
                n1c += p * bfhi(vc[j]);
            }
            ic += 4;
        }
    }
    float rw = 1.f / (denw + 1e-16f);
    float rc = 1.f / (denc + 1e-16f);
    float2 o;
    o.x = n0w * rw + n0c * rc;
    o.y = n1w * rw + n1c * rc;
    *reinterpret_cast<float2*>(&gat[(long)d * DHID + 2 * l]) = o;
}

// ---------------------------------------------------------------------------
// GraphNorm reduction: per-column sum and sum-of-squares of (gat + bsum)
// ---------------------------------------------------------------------------
#define GN_ROWS 128
__global__ void gn_reduce(const float* __restrict__ gat, const float* __restrict__ bsum,
                          float* __restrict__ colsum, float* __restrict__ colsumsq, int Np) {
    int t = threadIdx.x;
    long r0 = (long)blockIdx.x * GN_ROWS;
    long r1 = min(r0 + GN_ROWS, (long)Np);
    float b = bsum[t], s1 = 0.f, s2 = 0.f;
    for (long r = r0; r < r1; ++r) {
        float xv = gat[r * DHID + t] + b;
        s1 += xv;
        s2 += xv * xv;
    }
    atomAddF(colsum + t, s1);
    atomAddF(colsumsq + t, s2);
}

// ---------------------------------------------------------------------------
// Final paper via MFMA: nrm = (gat+bsum)*cscale + cshift (bf16 in LDS), @W2 + b2.
// ---------------------------------------------------------------------------
__global__ __launch_bounds__(256) void final_mfma(
    const float* __restrict__ gat, const float* __restrict__ bsum,
    const float* __restrict__ colsum, const float* __restrict__ colsumsq,
    const float* __restrict__ gnw, const float* __restrict__ gnb,
    const float* __restrict__ gnm,
    const unsigned short* __restrict__ W2P, const float* __restrict__ b2,
    float* __restrict__ out, int Np) {
    __shared__ unsigned short xt[BM * LDST];
    __shared__ float cscale[DHID], cshift[DHID];
    int t = threadIdx.x;
    int lane = t & 63, w = t >> 6;
    long row0 = (long)blockIdx.x * BM;
    if (t < DHID) {
        float invN = 1.f / (float)Np;
        float mu = colsum[t] * invN;
        float ms = gnm[t];
        float var = colsumsq[t] * invN - mu * mu * ms * (2.f - ms);
        float sc = gnw[t] * rsqrtf(var + GN_EPS);
        cscale[t] = sc;
        cshift[t] = (bsum[t] - ms * mu) * sc + gnb[t];
    }
    __syncthreads();
    for (int it = 0; it < 16; ++it) {
        int idx2 = t + it * 256;
        int r = idx2 >> 6, cp = idx2 & 63;
        long gr = row0 + r;
        float v0 = 0.f, v1 = 0.f;
        if (gr < Np) {
            v0 = gat[gr * DHID + 2 * cp] * cscale[2 * cp] + cshift[2 * cp];
            v1 = gat[gr * DHID + 2 * cp + 1] * cscale[2 * cp + 1] + cshift[2 * cp + 1];
        }
        uint32_t pk = (uint32_t)f2bf(v0) | ((uint32_t)f2bf(v1) << 16);
        *reinterpret_cast<uint32_t*>(&xt[r * LDST + 2 * cp]) = pk;
    }
    __syncthreads();
    int arow = w * 16 + (lane & 15);
    int koff = (lane >> 4) << 3;
    short8 af[4];
#pragma unroll
    for (int kk = 0; kk < 4; ++kk)
        af[kk] = *reinterpret_cast<const short8*>(&xt[arow * LDST + kk * 32 + koff]);
    const short8* Bw = reinterpret_cast<const short8*>(W2P);
    int orow = w * 16 + ((lane >> 4) << 2);
    int ccol = lane & 15;
#pragma unroll
    for (int nt = 0; nt < 8; ++nt) {
        f32x4 a = {0.f, 0.f, 0.f, 0.f};
#pragma unroll
        for (int kk = 0; kk < 4; ++kk)
            a = __builtin_amdgcn_mfma_f32_16x16x32_bf16(af[kk], Bw[(nt * 4 + kk) * 64 + lane], a, 0, 0, 0);
        float b = b2[nt * 16 + ccol];
#pragma unroll
        for (int r = 0; r < 4; ++r) {
            long gr = row0 + orow + r;
            if (gr < Np) out[gr * DHID + nt * 16 + ccol] = a[r] + b;
        }
    }
}

// ---------------------------------------------------------------------------
// Author output: gnorm(zeros) == gnb, so every row = gnb@W2_author + b2_author
// ---------------------------------------------------------------------------
__global__ void author_row(const float* __restrict__ gnb_a, const float* __restrict__ W2a,
                           const float* __restrict__ b2a, float* __restrict__ row_a) {
    int t = threadIdx.x;
    float acc = b2a[t];
    for (int k = 0; k < DHID; ++k) acc += gnb_a[k] * W2a[k * DHID + t];
    row_a[t] = acc;
}

__global__ void fill_author(const float* __restrict__ row_a, float4* __restrict__ out, long n4) {
    long i = (long)blockIdx.x * blockDim.x + threadIdx.x;
    if (i < n4) out[i] = reinterpret_cast<const float4*>(row_a)[i & 31];
}

// ---------------------------------------------------------------------------
extern "C" void kernel_launch(void* const* d_in, const int* in_sizes, int n_in,
                              void* d_out, int out_size, void* d_ws, size_t ws_size,
                              hipStream_t stream) {
    const float* x_p   = (const float*)d_in[0];
    const float* x_a   = (const float*)d_in[1];
    const int*   e_w   = (const int*)d_in[2];
    const int*   e_c   = (const int*)d_in[3];
    const float* Wlp   = (const float*)d_in[4];
    const float* blp   = (const float*)d_in[5];
    const float* Wla   = (const float*)d_in[6];
    const float* bla   = (const float*)d_in[7];
    const float* Wsw   = (const float*)d_in[8];
    const float* Wdw   = (const float*)d_in[9];
    const float* asw   = (const float*)d_in[10];
    const float* adw   = (const float*)d_in[11];
    const float* bw    = (const float*)d_in[12];
    const float* Wsc   = (const float*)d_in[13];
    const float* Wdc   = (const float*)d_in[14];
    const float* asc   = (const float*)d_in[15];
    const float* adc   = (const float*)d_in[16];
    const float* bc    = (const float*)d_in[17];
    const float* gnw_p = (const float*)d_in[18];
    const float* gnb_p = (const float*)d_in[19];
    const float* gnm_p = (const float*)d_in[20];
    const float* gnb_a = (const float*)d_in[22];
    const float* W2p   = (const float*)d_in[24];
    const float* b2p   = (const float*)d_in[25];
    const float* W2a   = (const float*)d_in[26];
    const float* b2a   = (const float*)d_in[27];

    int Np = in_sizes[0] / DHID;
    int Na = in_sizes[1] / DHID;
    int Ew = in_sizes[2] / 2;
    int Ec = in_sizes[3] / 2;
    int nself_w = Na < Np ? Na : Np;
    int nself_c = Np;
    int tot_w = Ew + nself_w;
    int tot_c = Ec + nself_c;
    int tot_all = tot_w + tot_c;
    int maxTot = tot_all + 6 * Np + 8;     // pad bound: +3 per segment, 2Np segments

    float* ws = (float*)d_ws;
    float* gat   = ws;                                 // Np*128
    float* a_d_w = gat + (size_t)Np * DHID;            // Np*8
    float* a_d_c = a_d_w + (size_t)Np * H;             // Np*8
    float* a_s_w = a_d_c + (size_t)Np * H;             // (Na+1)*8
    float* a_s_c = a_s_w + (size_t)(Na + 1) * H;       // (Np+1)*8
    float* Vp    = a_s_c + (size_t)(Np + 1) * H;       // 128*24
    float* Va    = Vp + DHID * 24;                     // 128*8
    float* bsum  = Va + DHID * H;                      // 128
    float* row_a = bsum + DHID;                        // 128
    // ---- zeroed region (one contiguous memset) ----
    float* colsum   = row_a + DHID;                    // 128
    float* colsumsq = colsum + DHID;                   // 128
    int*   deg      = (int*)(colsumsq + DHID);         // 2*Np
    size_t zero_bytes = (2 * DHID) * sizeof(float) + 2 * (size_t)Np * sizeof(int);
    // ---- CSR arrays ----
    int* off  = deg + 2 * Np;                          // 2*Np + 1
    int* cur  = off + 2 * Np + 1;                      // 2*Np
    int* bs1  = cur + 2 * Np;                          // 512
    int* bs2  = bs1 + 512;                             // 512
    uintptr_t up = (uintptr_t)(bs2 + 512);
    up = (up + 15) & ~(uintptr_t)15;
    int* srcu = (int*)up;                              // maxTot (16B aligned)
    // ---- bf16 message arrays (one phantom row each) ----
    unsigned short* xs_w = (unsigned short*)(srcu + maxTot);  // (Na+1)*128
    unsigned short* xs_c = xs_w + (size_t)(Na + 1) * DHID;    // (Np+1)*128
    // ---- bf16 packed weight fragments (16B-aligned) ----
    up = (uintptr_t)(xs_c + (size_t)(Np + 1) * DHID);
    up = (up + 15) & ~(uintptr_t)15;
    unsigned short* WlinP_p = (unsigned short*)up;         // 16384 each
    unsigned short* WsrcP_c = WlinP_p + 16384;
    unsigned short* WlinP_a = WsrcP_c + 16384;
    unsigned short* WsrcP_w = WlinP_a + 16384;
    unsigned short* W2P_p   = WsrcP_w + 16384;
    unsigned short* VscP_p  = W2P_p + 16384;               // 4096
    unsigned short* VscP_a  = VscP_p + 4096;               // 2048

    hipMemsetAsync(colsum, 0, zero_bytes, stream);

    fold_kernel<<<4, 128, 0, stream>>>(Wsw, asw, Wdw, adw, Wsc, asc, Wdc, adc,
                                       bw, bc, Vp, Va, bsum);

    // ---- pack all weights in one launch ----
    {
        PackArgs pa;
        const float* Ws[7] = {Wlp, Wsc, Wla, Wsw, W2p, Vp, Va};
        unsigned short* Os[7] = {WlinP_p, WsrcP_c, WlinP_a, WsrcP_w, W2P_p, VscP_p, VscP_a};
        int lds_[7] = {DHID, DHID, DHID, DHID, DHID, 24, 8};
        int ncs[7] = {DHID, DHID, DHID, DHID, DHID, 24, 8};
        int nts[7] = {8, 8, 8, 8, 8, 2, 1};
        for (int j = 0; j < 7; ++j) {
            pa.W[j] = Ws[j]; pa.out[j] = Os[j];
            pa.ldw[j] = lds_[j]; pa.ncols[j] = ncs[j]; pa.ntiles[j] = nts[j];
        }
        pack_all<<<dim3(8, 7), 256, 0, stream>>>(pa);
    }

    // ---- MFMA projections ----
    proj_mfma<2><<<(Np + BM - 1) / BM, 256, 0, stream>>>(
        x_p, Np, WlinP_p, blp, WsrcP_c, VscP_p, xs_c, a_d_w, a_s_c, a_d_c);
    proj_mfma<1><<<(Na + BM - 1) / BM, 256, 0, stream>>>(
        x_a, Na, WlinP_a, bla, WsrcP_w, VscP_a, xs_w, a_s_w, nullptr, nullptr);

    // ---- unified CSR build (padded segments, phantom fill) ----
    deg_hist<<<(tot_all + 255) / 256, 256, 0, stream>>>(
        e_w + Ew, Ew, nself_w, e_c + Ec, Ec, nself_c, Np, deg,
        xs_w + (size_t)Na * DHID, a_s_w + (size_t)Na * H,
        xs_c + (size_t)Np * DHID, a_s_c + (size_t)Np * H);
    int n2 = 2 * Np;
    int nb = (n2 + SCAN_T * SCAN_I - 1) / (SCAN_T * SCAN_I);
    scan1<<<nb, SCAN_T, 0, stream>>>(deg, n2, off, bs1, 1, nullptr);
    scan1<<<1, SCAN_T, 0, stream>>>(bs1, nb, bs1, bs2, 0, off + n2);
    scan3<<<(n2 + 255) / 256, 256, 0, stream>>>(off, bs1, n2, cur);
    prefill<<<(maxTot + 255) / 256, 256, 0, stream>>>(off, Np, Na, srcu);
    csr_scatter<<<(tot_all + 255) / 256, 256, 0, stream>>>(
        e_w, e_w + Ew, Ew, nself_w, e_c, e_c + Ec, Ec, nself_c, Np, cur, srcu);

    // ---- fused gather: both edge types interleaved, padded batch-4 MLP ----
    gat_gather<<<(Np + 3) / 4, 256, 0, stream>>>(off, srcu,
                                                 a_s_w, a_d_w, a_s_c, a_d_c,
                                                 xs_w, xs_c, gat, Np);

    gn_reduce<<<(Np + GN_ROWS - 1) / GN_ROWS, 128, 0, stream>>>(gat, bsum, colsum, colsumsq, Np);

    final_mfma<<<(Np + BM - 1) / BM, 256, 0, stream>>>(
        gat, bsum, colsum, colsumsq, gnw_p, gnb_p, gnm_p, W2P_p, b2p, (float*)d_out, Np);

    author_row<<<1, 128, 0, stream>>>(gnb_a, W2a, b2a, row_a);
    {
        long n4 = (long)Na * DHID / 4;
        fill_author<<<(n4 + 255) / 256, 256, 0, stream>>>(
            row_a, (float4*)((float*)d_out + (size_t)Np * DHID), n4);
    }
}

// Round 7
// 308.279 us; speedup vs baseline: 2.5258x; 1.1922x over previous
//
#include <hip/hip_runtime.h>
#include <cstdint>
#include <cstddef>

#define H 8
#define DHID 128
#define BM 64            // rows per MFMA block
#define LDST 136         // padded LDS row stride (bf16 elems)
#define NEG_SLOPE 0.2f
#define GN_EPS 1e-5f

#define SCAN_T 256
#define SCAN_I 4         // 1024 elements per scan block

typedef __attribute__((ext_vector_type(8))) short short8;
typedef __attribute__((ext_vector_type(4))) float f32x4;

__device__ __forceinline__ void atomAddF(float* p, float v) {
    __hip_atomic_fetch_add(p, v, __ATOMIC_RELAXED, __HIP_MEMORY_SCOPE_AGENT);
}
__device__ __forceinline__ unsigned short f2bf(float f) {
    uint32_t u = __float_as_uint(f);
    uint32_t r = (u + 0x7FFFu + ((u >> 16) & 1u)) >> 16;
    return (unsigned short)r;
}
__device__ __forceinline__ float bflo(uint32_t v) { return __uint_as_float(v << 16); }
__device__ __forceinline__ float bfhi(uint32_t v) { return __uint_as_float(v & 0xFFFF0000u); }

// ---------------------------------------------------------------------------
// K1: prep (pack weights -> MFMA B-frags with attention fold inline, misc init)
//     ∥ deg_hist (both edge types + self loops).
// pack mapping: out[((nt*4+kk)*64+lane)*8+i] = W[kk*32+(lane>>4)*8+i][nt*16+(lane&15)]
// ---------------------------------------------------------------------------
struct PrepHist {
    const float *Wlp, *Wsc, *Wla, *Wsw, *W2p;
    const float *Wdw, *adw, *asc_, *Wdc, *adc_, *asw_;
    unsigned short *WlinP_p, *WsrcP_c, *WlinP_a, *WsrcP_w, *W2P_p, *VscP_p, *VscP_a;
    const float *bw, *bc, *gnb_a, *W2a, *b2a;
    float *bsum, *row_a, *colsum, *colsumsq;
    unsigned short *xs_w_ph, *xs_c_ph;
    float *as_w_ph, *as_c_ph;
    const int *dst_w, *dst_c;
    int *deg;
    int Ew, nself_w, Ec, nself_c, Np, HB0;
};

__global__ void prep_hist(PrepHist a) {
    int b = blockIdx.x, t = threadIdx.x;
    if (b >= a.HB0) {
        int i = (b - a.HB0) * 256 + t;
        int tw = a.Ew + a.nself_w;
        if (i < tw) {
            int d = (i < a.Ew) ? a.dst_w[i] : (i - a.Ew);
            atomicAdd(&a.deg[d], 1);
        } else {
            int j = i - tw;
            if (j < a.Ec + a.nself_c) {
                int d = (j < a.Ec) ? a.dst_c[j] : (j - a.Ec);
                atomicAdd(&a.deg[a.Np + d], 1);
            }
        }
        return;
    }
    if (b == 56) {
        if (t < 128) {
            a.bsum[t] = a.bw[t] + a.bc[t];
            float acc = a.b2a[t];
            for (int k = 0; k < DHID; ++k) acc += a.gnb_a[k] * a.W2a[k * DHID + t];
            a.row_a[t] = acc;
            a.colsum[t] = 0.f;
            a.colsumsq[t] = 0.f;
            a.xs_w_ph[t] = 0;
            a.xs_c_ph[t] = 0;
        } else if (t < 136) a.as_w_ph[t - 128] = -1e30f;
        else if (t < 144) a.as_c_ph[t - 136] = -1e30f;
        return;
    }
    int j = b >> 3;
    int idx = (b & 7) * 256 + t;
    int lane = idx & 63, kk = (idx >> 6) & 3, nt = idx >> 8;
    int col = nt * 16 + (lane & 15);
    int k0 = kk * 32 + ((lane >> 4) << 3);
    if (j < 5) {
        const float* W = j == 0 ? a.Wlp : j == 1 ? a.Wsc : j == 2 ? a.Wla : j == 3 ? a.Wsw : a.W2p;
        unsigned short* out = j == 0 ? a.WlinP_p : j == 1 ? a.WsrcP_c : j == 2 ? a.WlinP_a
                              : j == 3 ? a.WsrcP_w : a.W2P_p;
        for (int i = 0; i < 8; ++i) out[idx * 8 + i] = f2bf(W[(k0 + i) * DHID + col]);
    } else if (j == 5) {
        if (idx >= 2 * 256) return;
        const float *W = nullptr, *A = nullptr;
        int h = col & 7;
        if (col < 24) {
            int which = col >> 3;
            W = which == 0 ? a.Wdw : which == 1 ? a.Wsc : a.Wdc;
            A = which == 0 ? a.adw : which == 1 ? a.asc_ : a.adc_;
        }
        for (int i = 0; i < 8; ++i) {
            float v = 0.f;
            if (W)
                for (int c = 0; c < 16; ++c) v += W[(k0 + i) * DHID + h * 16 + c] * A[h * 16 + c];
            a.VscP_p[idx * 8 + i] = f2bf(v);
        }
    } else {
        if (idx >= 256) return;
        int h = col & 7;
        for (int i = 0; i < 8; ++i) {
            float v = 0.f;
            if (col < 8)
                for (int c = 0; c < 16; ++c)
                    v += a.Wsw[(k0 + i) * DHID + h * 16 + c] * a.asw_[h * 16 + c];
            a.VscP_a[idx * 8 + i] = f2bf(v);
        }
    }
}

// ---------------------------------------------------------------------------
// Exclusive scan pass 1. pad!=0 rounds each value up to multiple of 4.
// ---------------------------------------------------------------------------
__global__ void scan1(const int* __restrict__ in, int n, int* __restrict__ out,
                      int* __restrict__ bsums, int pad, int* __restrict__ totalOut) {
    __shared__ int sh[SCAN_T];
    int t = threadIdx.x;
    long base = (long)blockIdx.x * SCAN_T * SCAN_I;
    int v[SCAN_I];
    int s = 0;
#pragma unroll
    for (int j = 0; j < SCAN_I; ++j) {
        long idx = base + (long)t * SCAN_I + j;
        int x = (idx < n) ? in[idx] : 0;
        if (pad) x = (x + 3) & ~3;
        v[j] = x;
        s += x;
    }
    sh[t] = s;
    __syncthreads();
    for (int off = 1; off < SCAN_T; off <<= 1) {
        int x = (t >= off) ? sh[t - off] : 0;
        __syncthreads();
        sh[t] += x;
        __syncthreads();
    }
    int run = sh[t] - s;
#pragma unroll
    for (int j = 0; j < SCAN_I; ++j) {
        long idx = base + (long)t * SCAN_I + j;
        if (idx < n) out[idx] = run;
        run += v[j];
    }
    if (t == SCAN_T - 1) {
        bsums[blockIdx.x] = sh[SCAN_T - 1];
        if (totalOut) *totalOut = sh[SCAN_T - 1];
    }
}

// ---------------------------------------------------------------------------
// scan3 (off_raw+bs1 -> off2, cur) ∥ prefill of srcu with phantom ids.
// Race-free: off_raw read-only here; mid recomputed from off_raw + bs1.
// ---------------------------------------------------------------------------
__global__ void scan3_prefill(const int* __restrict__ off_raw, const int* __restrict__ bs1,
                              int n2, int* __restrict__ off2, int* __restrict__ cur,
                              int Np, int Na, int maxTot, int* __restrict__ srcu) {
    int i = blockIdx.x * 256 + threadIdx.x;
    if (i < n2) {
        int v = off_raw[i] + bs1[i / (SCAN_T * SCAN_I)];
        off2[i] = v;
        cur[i] = v;
    }
    int mid = off_raw[Np] + bs1[Np / (SCAN_T * SCAN_I)];
    long stride = (long)gridDim.x * 256;
    for (long k = i; k < maxTot; k += stride) srcu[k] = (k < (long)mid) ? Na : Np;
}

// ---------------------------------------------------------------------------
// MFMA projection body (paper NSC=2 / author NSC=1)
// ---------------------------------------------------------------------------
template <int NSC>
__device__ void proj_body(unsigned short* xt, int bid,
                          const float* __restrict__ x, int nrows,
                          const unsigned short* __restrict__ WlinP, const float* __restrict__ blin,
                          const unsigned short* __restrict__ WsrcP,
                          const unsigned short* __restrict__ VscP,
                          unsigned short* __restrict__ xs,
                          float* __restrict__ a0, float* __restrict__ a1, float* __restrict__ a2) {
    int t = threadIdx.x;
    int lane = t & 63, w = t >> 6;
    long row0 = (long)bid * BM;
    for (int it = 0; it < 16; ++it) {
        int idx2 = t + it * 256;
        int r = idx2 >> 6, cp = idx2 & 63;
        long gr = row0 + r;
        float v0 = 0.f, v1 = 0.f;
        if (gr < nrows) { v0 = x[gr * DHID + 2 * cp]; v1 = x[gr * DHID + 2 * cp + 1]; }
        uint32_t pk = (uint32_t)f2bf(v0) | ((uint32_t)f2bf(v1) << 16);
        *reinterpret_cast<uint32_t*>(&xt[r * LDST + 2 * cp]) = pk;
    }
    __syncthreads();
    int arow = w * 16 + (lane & 15);
    int koff = (lane >> 4) << 3;
    short8 af[4];
#pragma unroll
    for (int kk = 0; kk < 4; ++kk)
        af[kk] = *reinterpret_cast<const short8*>(&xt[arow * LDST + kk * 32 + koff]);
    const short8* Bl = reinterpret_cast<const short8*>(WlinP);
    f32x4 acc[8];
#pragma unroll
    for (int nt = 0; nt < 8; ++nt) {
        f32x4 a = {0.f, 0.f, 0.f, 0.f};
#pragma unroll
        for (int kk = 0; kk < 4; ++kk)
            a = __builtin_amdgcn_mfma_f32_16x16x32_bf16(af[kk], Bl[(nt * 4 + kk) * 64 + lane], a, 0, 0, 0);
        acc[nt] = a;
    }
    __syncthreads();
    int orow = w * 16 + ((lane >> 4) << 2);
    int ccol = lane & 15;
#pragma unroll
    for (int nt = 0; nt < 8; ++nt) {
        float b = blin[nt * 16 + ccol];
#pragma unroll
        for (int r = 0; r < 4; ++r) {
            float e = fmaxf(acc[nt][r] + b, 0.f);
            xt[(orow + r) * LDST + nt * 16 + ccol] = f2bf(e);
        }
    }
    __syncthreads();
#pragma unroll
    for (int kk = 0; kk < 4; ++kk)
        af[kk] = *reinterpret_cast<const short8*>(&xt[arow * LDST + kk * 32 + koff]);
    const short8* Bs = reinterpret_cast<const short8*>(WsrcP);
#pragma unroll
    for (int nt = 0; nt < 8; ++nt) {
        f32x4 a = {0.f, 0.f, 0.f, 0.f};
#pragma unroll
        for (int kk = 0; kk < 4; ++kk)
            a = __builtin_amdgcn_mfma_f32_16x16x32_bf16(af[kk], Bs[(nt * 4 + kk) * 64 + lane], a, 0, 0, 0);
        acc[nt] = a;
    }
    const short8* Bv = reinterpret_cast<const short8*>(VscP);
    f32x4 sacc0 = {0.f, 0.f, 0.f, 0.f}, sacc1 = {0.f, 0.f, 0.f, 0.f};
#pragma unroll
    for (int kk = 0; kk < 4; ++kk)
        sacc0 = __builtin_amdgcn_mfma_f32_16x16x32_bf16(af[kk], Bv[kk * 64 + lane], sacc0, 0, 0, 0);
    if (NSC > 1) {
#pragma unroll
        for (int kk = 0; kk < 4; ++kk)
            sacc1 = __builtin_amdgcn_mfma_f32_16x16x32_bf16(af[kk], Bv[(4 + kk) * 64 + lane], sacc1, 0, 0, 0);
    }
#pragma unroll
    for (int nt = 0; nt < 8; ++nt) {
#pragma unroll
        for (int r = 0; r < 4; ++r) {
            long gr = row0 + orow + r;
            if (gr < nrows) xs[gr * DHID + nt * 16 + ccol] = f2bf(acc[nt][r]);
        }
    }
#pragma unroll
    for (int st = 0; st < NSC; ++st) {
        int scol = st * 16 + ccol;
        int h = scol & 7, which = scol >> 3;
        float* ap = which == 0 ? a0 : which == 1 ? a1 : which == 2 ? a2 : nullptr;
        if (ap) {
            f32x4 s = st == 0 ? sacc0 : sacc1;
#pragma unroll
            for (int r = 0; r < 4; ++r) {
                long gr = row0 + orow + r;
                if (gr < nrows) ap[gr * H + h] = s[r];
            }
        }
    }
}

// ---------------------------------------------------------------------------
// K4 MEGA: proj_paper ∥ proj_author ∥ csr_scatter
// ---------------------------------------------------------------------------
struct MegaArgs {
    const float* x_p; int Np;
    const unsigned short* WlinP_p; const float* blp;
    const unsigned short* WsrcP_c; const unsigned short* VscP_p;
    unsigned short* xs_c; float *a_d_w, *a_s_c, *a_d_c;
    const float* x_a; int Na;
    const unsigned short* WlinP_a; const float* bla;
    const unsigned short* WsrcP_w; const unsigned short* VscP_a;
    unsigned short* xs_w; float* a_s_w;
    const int *src_w, *dst_w, *src_c, *dst_c;
    int Ew, nself_w, Ec, nself_c;
    int *cur, *srcu;
    int PB, AB;
};

__global__ __launch_bounds__(256) void mega(MegaArgs a) {
    __shared__ unsigned short xt[BM * LDST];
    int b = blockIdx.x;
    if (b < a.PB) {
        proj_body<2>(xt, b, a.x_p, a.Np, a.WlinP_p, a.blp, a.WsrcP_c, a.VscP_p,
                     a.xs_c, a.a_d_w, a.a_s_c, a.a_d_c);
        return;
    }
    if (b < a.PB + a.AB) {
        proj_body<1>(xt, b - a.PB, a.x_a, a.Na, a.WlinP_a, a.bla, a.WsrcP_w, a.VscP_a,
                     a.xs_w, a.a_s_w, nullptr, nullptr);
        return;
    }
    int i = (b - a.PB - a.AB) * 256 + threadIdx.x;
    int tw = a.Ew + a.nself_w;
    int s, di;
    if (i < tw) {
        if (i < a.Ew) { s = a.src_w[i]; di = a.dst_w[i]; } else { s = di = i - a.Ew; }
    } else {
        int j = i - tw;
        if (j >= a.Ec + a.nself_c) return;
        if (j < a.Ec) { s = a.src_c[j]; di = a.Np + a.dst_c[j]; }
        else { s = j - a.Ec; di = a.Np + (j - a.Ec); }
    }
    int pos = atomicAdd(&a.cur[di], 1);
    a.srcu[pos] = s;
}

// ---------------------------------------------------------------------------
// Gather (unchanged from round 6; off -> off2)
// ---------------------------------------------------------------------------
__global__ __launch_bounds__(256) void gat_gather(
    const int* __restrict__ off, const int* __restrict__ srcu,
    const float* __restrict__ a_s_w, const float* __restrict__ a_d_w,
    const float* __restrict__ a_s_c, const float* __restrict__ a_d_c,
    const unsigned short* __restrict__ xs_w, const unsigned short* __restrict__ xs_c,
    float* __restrict__ gat, int Np) {
    int l = threadIdx.x & 63;
    int d = blockIdx.x * 4 + (threadIdx.x >> 6);
    if (d >= Np) return;
    int h = l >> 3;
    int iw = off[d], w1 = off[d + 1];
    int ic = off[Np + d], c1 = off[Np + d + 1];
    float adw = a_d_w[(long)d * H + h];
    float adc = a_d_c[(long)d * H + h];
    float denw = 0.f, n0w = 0.f, n1w = 0.f;
    float denc = 0.f, n0c = 0.f, n1c = 0.f;
    while (iw < w1 || ic < c1) {
        bool hw = iw < w1, hc = ic < c1;
        int4 sw, sc;
        if (hw) sw = *reinterpret_cast<const int4*>(srcu + iw);
        if (hc) sc = *reinterpret_cast<const int4*>(srcu + ic);
        float ew[4], ec[4];
        uint32_t vw[4], vc[4];
        if (hw) {
            ew[0] = a_s_w[(long)sw.x * H + h];
            ew[1] = a_s_w[(long)sw.y * H + h];
            ew[2] = a_s_w[(long)sw.z * H + h];
            ew[3] = a_s_w[(long)sw.w * H + h];
            vw[0] = *reinterpret_cast<const uint32_t*>(xs_w + (long)sw.x * DHID + 2 * l);
            vw[1] = *reinterpret_cast<const uint32_t*>(xs_w + (long)sw.y * DHID + 2 * l);
            vw[2] = *reinterpret_cast<const uint32_t*>(xs_w + (long)sw.z * DHID + 2 * l);
            vw[3] = *reinterpret_cast<const uint32_t*>(xs_w + (long)sw.w * DHID + 2 * l);
        }
        if (hc) {
            ec[0] = a_s_c[(long)sc.x * H + h];
            ec[1] = a_s_c[(long)sc.y * H + h];
            ec[2] = a_s_c[(long)sc.z * H + h];
            ec[3] = a_s_c[(long)sc.w * H + h];
            vc[0] = *reinterpret_cast<const uint32_t*>(xs_c + (long)sc.x * DHID + 2 * l);
            vc[1] = *reinterpret_cast<const uint32_t*>(xs_c + (long)sc.y * DHID + 2 * l);
            vc[2] = *reinterpret_cast<const uint32_t*>(xs_c + (long)sc.z * DHID + 2 * l);
            vc[3] = *reinterpret_cast<const uint32_t*>(xs_c + (long)sc.w * DHID + 2 * l);
        }
        if (hw) {
#pragma unroll
            for (int j = 0; j < 4; ++j) {
                float e = ew[j] + adw;
                e = e > 0.f ? e : NEG_SLOPE * e;
                float p = __expf(e);
                denw += p;
                n0w += p * bflo(vw[j]);
                n1w += p * bfhi(vw[j]);
            }
            iw += 4;
        }
        if (hc) {
#pragma unroll
            for (int j = 0; j < 4; ++j) {
                float e = ec[j] + adc;
                e = e > 0.f ? e : NEG_SLOPE * e;
                float p = __expf(e);
                denc += p;
                n0c += p * bflo(vc[j]);
                n1c += p * bfhi(vc[j]);
            }
            ic += 4;
        }
    }
    float rw = 1.f / (denw + 1e-16f);
    float rc = 1.f / (denc + 1e-16f);
    float2 o;
    o.x = n0w * rw + n0c * rc;
    o.y = n1w * rw + n1c * rc;
    *reinterpret_cast<float2*>(&gat[(long)d * DHID + 2 * l]) = o;
}

// ---------------------------------------------------------------------------
// GraphNorm reduction
// ---------------------------------------------------------------------------
#define GN_ROWS 128
__global__ void gn_reduce(const float* __restrict__ gat, const float* __restrict__ bsum,
                          float* __restrict__ colsum, float* __restrict__ colsumsq, int Np) {
    int t = threadIdx.x;
    long r0 = (long)blockIdx.x * GN_ROWS;
    long r1 = min(r0 + GN_ROWS, (long)Np);
    float b = bsum[t], s1 = 0.f, s2 = 0.f;
    for (long r = r0; r < r1; ++r) {
        float xv = gat[r * DHID + t] + b;
        s1 += xv;
        s2 += xv * xv;
    }
    atomAddF(colsum + t, s1);
    atomAddF(colsumsq + t, s2);
}

// ---------------------------------------------------------------------------
// K7: final_mfma (paper gnorm + @W2 + b2) ∥ author broadcast fill
// ---------------------------------------------------------------------------
__global__ __launch_bounds__(256) void final_fill(
    const float* __restrict__ gat, const float* __restrict__ bsum,
    const float* __restrict__ colsum, const float* __restrict__ colsumsq,
    const float* __restrict__ gnw, const float* __restrict__ gnb,
    const float* __restrict__ gnm,
    const unsigned short* __restrict__ W2P, const float* __restrict__ b2,
    float* __restrict__ out, int Np, int FB,
    const float* __restrict__ row_a, float4* __restrict__ outa, long n4) {
    __shared__ unsigned short xt[BM * LDST];
    __shared__ float cscale[DHID], cshift[DHID];
    int b = blockIdx.x;
    int t = threadIdx.x;
    if (b >= FB) {
        long i = (long)(b - FB) * 256 + t;
        long stride = (long)(gridDim.x - FB) * 256;
        const float4* r4 = reinterpret_cast<const float4*>(row_a);
        for (; i < n4; i += stride) outa[i] = r4[i & 31];
        return;
    }
    int lane = t & 63, w = t >> 6;
    long row0 = (long)b * BM;
    if (t < DHID) {
        float invN = 1.f / (float)Np;
        float mu = colsum[t] * invN;
        float ms = gnm[t];
        float var = colsumsq[t] * invN - mu * mu * ms * (2.f - ms);
        float sc = gnw[t] * rsqrtf(var + GN_EPS);
        cscale[t] = sc;
        cshift[t] = (bsum[t] - ms * mu) * sc + gnb[t];
    }
    __syncthreads();
    for (int it = 0; it < 16; ++it) {
        int idx2 = t + it * 256;
        int r = idx2 >> 6, cp = idx2 & 63;
        long gr = row0 + r;
        float v0 = 0.f, v1 = 0.f;
        if (gr < Np) {
            v0 = gat[gr * DHID + 2 * cp] * cscale[2 * cp] + cshift[2 * cp];
            v1 = gat[gr * DHID + 2 * cp + 1] * cscale[2 * cp + 1] + cshift[2 * cp + 1];
        }
        uint32_t pk = (uint32_t)f2bf(v0) | ((uint32_t)f2bf(v1) << 16);
        *reinterpret_cast<uint32_t*>(&xt[r * LDST + 2 * cp]) = pk;
    }
    __syncthreads();
    int arow = w * 16 + (lane & 15);
    int koff = (lane >> 4) << 3;
    short8 af[4];
#pragma unroll
    for (int kk = 0; kk < 4; ++kk)
        af[kk] = *reinterpret_cast<const short8*>(&xt[arow * LDST + kk * 32 + koff]);
    const short8* Bw = reinterpret_cast<const short8*>(W2P);
    int orow = w * 16 + ((lane >> 4) << 2);
    int ccol = lane & 15;
#pragma unroll
    for (int nt = 0; nt < 8; ++nt) {
        f32x4 a = {0.f, 0.f, 0.f, 0.f};
#pragma unroll
        for (int kk = 0; kk < 4; ++kk)
            a = __builtin_amdgcn_mfma_f32_16x16x32_bf16(af[kk], Bw[(nt * 4 + kk) * 64 + lane], a, 0, 0, 0);
        float bb = b2[nt * 16 + ccol];
#pragma unroll
        for (int r = 0; r < 4; ++r) {
            long gr = row0 + orow + r;
            if (gr < Np) out[gr * DHID + nt * 16 + ccol] = a[r] + bb;
        }
    }
}

// ---------------------------------------------------------------------------
extern "C" void kernel_launch(void* const* d_in, const int* in_sizes, int n_in,
                              void* d_out, int out_size, void* d_ws, size_t ws_size,
                              hipStream_t stream) {
    const float* x_p   = (const float*)d_in[0];
    const float* x_a   = (const float*)d_in[1];
    const int*   e_w   = (const int*)d_in[2];
    const int*   e_c   = (const int*)d_in[3];
    const float* Wlp   = (const float*)d_in[4];
    const float* blp   = (const float*)d_in[5];
    const float* Wla   = (const float*)d_in[6];
    const float* bla   = (const float*)d_in[7];
    const float* Wsw   = (const float*)d_in[8];
    const float* Wdw   = (const float*)d_in[9];
    const float* asw   = (const float*)d_in[10];
    const float* adw   = (const float*)d_in[11];
    const float* bw    = (const float*)d_in[12];
    const float* Wsc   = (const float*)d_in[13];
    const float* Wdc   = (const float*)d_in[14];
    const float* asc   = (const float*)d_in[15];
    const float* adc   = (const float*)d_in[16];
    const float* bc    = (const float*)d_in[17];
    const float* gnw_p = (const float*)d_in[18];
    const float* gnb_p = (const float*)d_in[19];
    const float* gnm_p = (const float*)d_in[20];
    const float* gnb_a = (const float*)d_in[22];
    const float* W2p   = (const float*)d_in[24];
    const float* b2p   = (const float*)d_in[25];
    const float* W2a   = (const float*)d_in[26];
    const float* b2a   = (const float*)d_in[27];

    int Np = in_sizes[0] / DHID;
    int Na = in_sizes[1] / DHID;
    int Ew = in_sizes[2] / 2;
    int Ec = in_sizes[3] / 2;
    int nself_w = Na < Np ? Na : Np;
    int nself_c = Np;
    int tot_all = (Ew + nself_w) + (Ec + nself_c);
    int maxTot = tot_all + 6 * Np + 8;

    float* ws = (float*)d_ws;
    float* gat   = ws;                                 // Np*128
    float* a_d_w = gat + (size_t)Np * DHID;            // Np*8
    float* a_d_c = a_d_w + (size_t)Np * H;             // Np*8
    float* a_s_w = a_d_c + (size_t)Np * H;             // (Na+1)*8
    float* a_s_c = a_s_w + (size_t)(Na + 1) * H;       // (Np+1)*8
    float* bsum  = a_s_c + (size_t)(Np + 1) * H;       // 128
    float* row_a = bsum + DHID;                        // 128
    float* colsum   = row_a + DHID;                    // 128
    float* colsumsq = colsum + DHID;                   // 128
    int*   deg   = (int*)(colsumsq + DHID);            // 2*Np (memset)
    int* off_raw = deg + 2 * Np;                       // 2*Np
    int* off2    = off_raw + 2 * Np;                   // 2*Np + 1
    int* cur     = off2 + 2 * Np + 1;                  // 2*Np
    int* bs1     = cur + 2 * Np;                       // 512
    int* bs2     = bs1 + 512;                          // 512
    uintptr_t up = (uintptr_t)(bs2 + 512);
    up = (up + 15) & ~(uintptr_t)15;
    int* srcu = (int*)up;                              // maxTot
    unsigned short* xs_w = (unsigned short*)(srcu + maxTot);  // (Na+1)*128
    unsigned short* xs_c = xs_w + (size_t)(Na + 1) * DHID;    // (Np+1)*128
    up = (uintptr_t)(xs_c + (size_t)(Np + 1) * DHID);
    up = (up + 15) & ~(uintptr_t)15;
    unsigned short* WlinP_p = (unsigned short*)up;
    unsigned short* WsrcP_c = WlinP_p + 16384;
    unsigned short* WlinP_a = WsrcP_c + 16384;
    unsigned short* WsrcP_w = WlinP_a + 16384;
    unsigned short* W2P_p   = WsrcP_w + 16384;
    unsigned short* VscP_p  = W2P_p + 16384;
    unsigned short* VscP_a  = VscP_p + 4096;

    hipMemsetAsync(deg, 0, 2 * (size_t)Np * sizeof(int), stream);

    int HB = (tot_all + 255) / 256;
    {
        PrepHist pa;
        pa.Wlp = Wlp; pa.Wsc = Wsc; pa.Wla = Wla; pa.Wsw = Wsw; pa.W2p = W2p;
        pa.Wdw = Wdw; pa.adw = adw; pa.asc_ = asc; pa.Wdc = Wdc; pa.adc_ = adc; pa.asw_ = asw;
        pa.WlinP_p = WlinP_p; pa.WsrcP_c = WsrcP_c; pa.WlinP_a = WlinP_a;
        pa.WsrcP_w = WsrcP_w; pa.W2P_p = W2P_p; pa.VscP_p = VscP_p; pa.VscP_a = VscP_a;
        pa.bw = bw; pa.bc = bc; pa.gnb_a = gnb_a; pa.W2a = W2a; pa.b2a = b2a;
        pa.bsum = bsum; pa.row_a = row_a; pa.colsum = colsum; pa.colsumsq = colsumsq;
        pa.xs_w_ph = xs_w + (size_t)Na * DHID;
        pa.xs_c_ph = xs_c + (size_t)Np * DHID;
        pa.as_w_ph = a_s_w + (size_t)Na * H;
        pa.as_c_ph = a_s_c + (size_t)Np * H;
        pa.dst_w = e_w + Ew; pa.dst_c = e_c + Ec;
        pa.deg = deg;
        pa.Ew = Ew; pa.nself_w = nself_w; pa.Ec = Ec; pa.nself_c = nself_c;
        pa.Np = Np; pa.HB0 = 57;
        prep_hist<<<57 + HB, 256, 0, stream>>>(pa);
    }

    int n2 = 2 * Np;
    int nb = (n2 + SCAN_T * SCAN_I - 1) / (SCAN_T * SCAN_I);
    scan1<<<nb, SCAN_T, 0, stream>>>(deg, n2, off_raw, bs1, 1, nullptr);
    scan1<<<1, SCAN_T, 0, stream>>>(bs1, nb, bs1, bs2, 0, off2 + n2);

    scan3_prefill<<<(maxTot + 255) / 256, 256, 0, stream>>>(
        off_raw, bs1, n2, off2, cur, Np, Na, maxTot, srcu);

    {
        MegaArgs ma;
        ma.x_p = x_p; ma.Np = Np; ma.WlinP_p = WlinP_p; ma.blp = blp;
        ma.WsrcP_c = WsrcP_c; ma.VscP_p = VscP_p;
        ma.xs_c = xs_c; ma.a_d_w = a_d_w; ma.a_s_c = a_s_c; ma.a_d_c = a_d_c;
        ma.x_a = x_a; ma.Na = Na; ma.WlinP_a = WlinP_a; ma.bla = bla;
        ma.WsrcP_w = WsrcP_w; ma.VscP_a = VscP_a;
        ma.xs_w = xs_w; ma.a_s_w = a_s_w;
        ma.src_w = e_w; ma.dst_w = e_w + Ew; ma.src_c = e_c; ma.dst_c = e_c + Ec;
        ma.Ew = Ew; ma.nself_w = nself_w; ma.Ec = Ec; ma.nself_c = nself_c;
        ma.cur = cur; ma.srcu = srcu;
        ma.PB = (Np + BM - 1) / BM;
        ma.AB = (Na + BM - 1) / BM;
        int SB = (tot_all + 255) / 256;
        mega<<<ma.PB + ma.AB + SB, 256, 0, stream>>>(ma);
    }

    gat_gather<<<(Np + 3) / 4, 256, 0, stream>>>(off2, srcu,
                                                 a_s_w, a_d_w, a_s_c, a_d_c,
                                                 xs_w, xs_c, gat, Np);

    gn_reduce<<<(Np + GN_ROWS - 1) / GN_ROWS, 128, 0, stream>>>(gat, bsum, colsum, colsumsq, Np);

    {
        int FB = (Np + BM - 1) / BM;
        long n4 = (long)Na * DHID / 4;
        final_fill<<<FB + 391, 256, 0, stream>>>(
            gat, bsum, colsum, colsumsq, gnw_p, gnb_p, gnm_p, W2P_p, b2p,
            (float*)d_out, Np, FB,
            row_a, (float4*)((float*)d_out + (size_t)Np * DHID), n4);
    }
}